// Round 1
// baseline (8396.689 us; speedup 1.0000x reference)
//
#include <hip/hip_runtime.h>
#include <hip/hip_bf16.h>
#include <cstdint>

#define B_ 2
#define S_ 2048
#define D_ 1024
#define H_ 16
#define DK_ 64
#define HALF_ 32   // DK/2

// ---------------------------------------------------------------------------
// Kernel 1: QKV projection (out = x @ w^T) + RoPE epilogue, store (b,h,s,dk).
// 64x64 output tile, BK=32, block(16,16), 4x4 micro-tile per thread.
// A and W tiles stored k-major (transposed) in LDS so the inner loop reads
// are float4 (ds_read_b128) instead of stride-row scalar reads.
// ---------------------------------------------------------------------------
__global__ __launch_bounds__(256) void qkv_rope_kernel(
    const float* __restrict__ x,
    const float* __restrict__ w_q, const float* __restrict__ w_k,
    const float* __restrict__ w_v,
    float* __restrict__ q_out, float* __restrict__ k_out, float* __restrict__ v_out,
    const float* __restrict__ sin_tab, const float* __restrict__ cos_tab,
    const int* __restrict__ tpos)
{
    const int which = blockIdx.z;
    const float* __restrict__ w = (which == 0) ? w_q : (which == 1) ? w_k : w_v;
    float* __restrict__ out = (which == 0) ? q_out : (which == 1) ? k_out : v_out;

    __shared__ float As_t[32][68];   // [k][m], pad 68 -> 272B row stride (16B aligned)
    __shared__ float Ws_t[32][68];   // [k][n]

    const int tx = threadIdx.x;      // 0..15 -> n
    const int ty = threadIdx.y;      // 0..15 -> m
    const int tid = ty * 16 + tx;
    const int row0 = blockIdx.y * 64;   // M = B*S
    const int col0 = blockIdx.x * 64;   // N = D

    float acc[4][4] = {};

    for (int k0 = 0; k0 < D_; k0 += 32) {
        __syncthreads();
        #pragma unroll
        for (int t = 0; t < 2; ++t) {
            int idx = t * 256 + tid;          // 0..511 float4 slots
            int r  = idx >> 3;                // 0..63
            int c4 = idx & 7;                 // 0..7
            float4 a = *reinterpret_cast<const float4*>(
                &x[(size_t)(row0 + r) * D_ + k0 + c4 * 4]);
            As_t[c4*4+0][r] = a.x; As_t[c4*4+1][r] = a.y;
            As_t[c4*4+2][r] = a.z; As_t[c4*4+3][r] = a.w;
            float4 b = *reinterpret_cast<const float4*>(
                &w[(size_t)(col0 + r) * D_ + k0 + c4 * 4]);
            Ws_t[c4*4+0][r] = b.x; Ws_t[c4*4+1][r] = b.y;
            Ws_t[c4*4+2][r] = b.z; Ws_t[c4*4+3][r] = b.w;
        }
        __syncthreads();
        #pragma unroll
        for (int kk = 0; kk < 32; ++kk) {
            float4 av = *reinterpret_cast<const float4*>(&As_t[kk][ty * 4]);
            float4 bv = *reinterpret_cast<const float4*>(&Ws_t[kk][tx * 4]);
            float a[4] = {av.x, av.y, av.z, av.w};
            float b[4] = {bv.x, bv.y, bv.z, bv.w};
            #pragma unroll
            for (int mi = 0; mi < 4; ++mi)
                #pragma unroll
                for (int ni = 0; ni < 4; ++ni)
                    acc[mi][ni] = fmaf(a[mi], b[ni], acc[mi][ni]);
        }
    }

    // epilogue: RoPE (for q,k) + transposed store to (b, h, s, dk)
    const int head = col0 >> 6;        // 64-wide col tile == exactly one head
    const int dk0  = tx * 4;           // 0..60, pairs (dk0,dk0+1),(dk0+2,dk0+3)
    const int f0   = dk0 >> 1;

    #pragma unroll
    for (int mi = 0; mi < 4; ++mi) {
        int gi = row0 + ty * 4 + mi;   // global row in [0, B*S)
        int b_ = gi >> 11;             // / S_
        int s_ = gi & (S_ - 1);
        float v0 = acc[mi][0], v1 = acc[mi][1], v2 = acc[mi][2], v3 = acc[mi][3];
        if (which < 2) {
            int pos = tpos[gi];
            float sn0 = sin_tab[pos * HALF_ + f0];
            float cs0 = cos_tab[pos * HALF_ + f0];
            float sn1 = sin_tab[pos * HALF_ + f0 + 1];
            float cs1 = cos_tab[pos * HALF_ + f0 + 1];
            float e0 = cs0 * v0 - sn0 * v1;
            float o0 = sn0 * v0 + cs0 * v1;
            float e1 = cs1 * v2 - sn1 * v3;
            float o1 = sn1 * v2 + cs1 * v3;
            v0 = e0; v1 = o0; v2 = e1; v3 = o1;
        }
        size_t off = (((size_t)b_ * H_ + head) * S_ + s_) * DK_ + dk0;
        *reinterpret_cast<float4*>(&out[off]) = make_float4(v0, v1, v2, v3);
    }
}

// ---------------------------------------------------------------------------
// Kernel 2: causal flash attention, fp32, 64x64 Q/K tiles, online softmax.
// Q and K stored d-major (transposed) in LDS; P stored j-major; V row-major.
// All inner-loop LDS reads are float4 or broadcast (<=2-way conflicts).
// ---------------------------------------------------------------------------
__global__ __launch_bounds__(256) void flash_attn_kernel(
    const float* __restrict__ q, const float* __restrict__ k,
    const float* __restrict__ v, float* __restrict__ attn)
{
    __shared__ float Qs_t[64][68];   // [d][i]
    __shared__ float Ks_t[64][68];   // [d][j]
    __shared__ float Vs[64][68];     // [j][d]
    __shared__ float Ps_t[64][68];   // [j][i]
    __shared__ float m_s[64], l_s[64];

    const int tx = threadIdx.x, ty = threadIdx.y;
    const int tid = ty * 16 + tx;
    const int qb = blockIdx.x;       // 0..31
    const int bh = blockIdx.y;       // 0..31  (b*H + h)
    const size_t base = (size_t)bh * S_ * DK_;

    // load Q tile transposed
    #pragma unroll
    for (int t = 0; t < 4; ++t) {
        int idx = t * 256 + tid;     // 0..1023 float4 slots
        int r  = idx >> 4;           // 0..63
        int c4 = idx & 15;           // 0..15
        float4 a = *reinterpret_cast<const float4*>(
            &q[base + (size_t)(qb * 64 + r) * DK_ + c4 * 4]);
        Qs_t[c4*4+0][r] = a.x; Qs_t[c4*4+1][r] = a.y;
        Qs_t[c4*4+2][r] = a.z; Qs_t[c4*4+3][r] = a.w;
    }
    if (tid < 64) { m_s[tid] = -1e30f; l_s[tid] = 0.0f; }

    float o[4][4] = {};
    const float scale = 0.125f;      // 1/sqrt(64)

    for (int kb = 0; kb <= qb; ++kb) {
        __syncthreads();             // protect K/V/P LDS reuse (and Q/m/l init)
        #pragma unroll
        for (int t = 0; t < 4; ++t) {
            int idx = t * 256 + tid;
            int r  = idx >> 4;
            int c4 = idx & 15;
            float4 a = *reinterpret_cast<const float4*>(
                &k[base + (size_t)(kb * 64 + r) * DK_ + c4 * 4]);
            Ks_t[c4*4+0][r] = a.x; Ks_t[c4*4+1][r] = a.y;
            Ks_t[c4*4+2][r] = a.z; Ks_t[c4*4+3][r] = a.w;
            *reinterpret_cast<float4*>(&Vs[r][c4 * 4]) =
                *reinterpret_cast<const float4*>(
                    &v[base + (size_t)(kb * 64 + r) * DK_ + c4 * 4]);
        }
        __syncthreads();

        // S = Q K^T
        float sv[4][4] = {};
        #pragma unroll
        for (int d = 0; d < 64; ++d) {
            float4 av = *reinterpret_cast<const float4*>(&Qs_t[d][ty * 4]);
            float4 bv = *reinterpret_cast<const float4*>(&Ks_t[d][tx * 4]);
            float a[4] = {av.x, av.y, av.z, av.w};
            float b[4] = {bv.x, bv.y, bv.z, bv.w};
            #pragma unroll
            for (int mi = 0; mi < 4; ++mi)
                #pragma unroll
                for (int ni = 0; ni < 4; ++ni)
                    sv[mi][ni] = fmaf(a[mi], b[ni], sv[mi][ni]);
        }

        // scale + causal mask
        const int qi0 = qb * 64 + ty * 4;
        const int kj0 = kb * 64 + tx * 4;
        #pragma unroll
        for (int mi = 0; mi < 4; ++mi)
            #pragma unroll
            for (int ni = 0; ni < 4; ++ni)
                sv[mi][ni] = (kj0 + ni <= qi0 + mi) ? sv[mi][ni] * scale : -1e30f;

        // online softmax update (row groups = 16 consecutive lanes in a wave)
        float pbuf[4][4];
        #pragma unroll
        for (int mi = 0; mi < 4; ++mi) {
            const int i = ty * 4 + mi;
            float rmax = fmaxf(fmaxf(sv[mi][0], sv[mi][1]),
                               fmaxf(sv[mi][2], sv[mi][3]));
            #pragma unroll
            for (int off = 1; off < 16; off <<= 1)
                rmax = fmaxf(rmax, __shfl_xor(rmax, off, 64));
            float m_old = m_s[i];                 // read by all lanes (lockstep)
            float m_new = fmaxf(m_old, rmax);
            float psum = 0.f;
            #pragma unroll
            for (int ni = 0; ni < 4; ++ni) {
                pbuf[mi][ni] = __expf(sv[mi][ni] - m_new);
                psum += pbuf[mi][ni];
            }
            #pragma unroll
            for (int off = 1; off < 16; off <<= 1)
                psum += __shfl_xor(psum, off, 64);
            float factor = __expf(m_old - m_new); // identical across row group
            if (tx == 0) { m_s[i] = m_new; l_s[i] = l_s[i] * factor + psum; }
            #pragma unroll
            for (int ni = 0; ni < 4; ++ni) o[mi][ni] *= factor;
        }

        // write P transposed: Ps_t[j][i]
        #pragma unroll
        for (int ni = 0; ni < 4; ++ni) {
            *reinterpret_cast<float4*>(&Ps_t[tx * 4 + ni][ty * 4]) =
                make_float4(pbuf[0][ni], pbuf[1][ni], pbuf[2][ni], pbuf[3][ni]);
        }
        __syncthreads();

        // O += P @ V
        #pragma unroll
        for (int j = 0; j < 64; ++j) {
            float4 av = *reinterpret_cast<const float4*>(&Ps_t[j][ty * 4]);
            float4 bv = *reinterpret_cast<const float4*>(&Vs[j][tx * 4]);
            float a[4] = {av.x, av.y, av.z, av.w};
            float b[4] = {bv.x, bv.y, bv.z, bv.w};
            #pragma unroll
            for (int mi = 0; mi < 4; ++mi)
                #pragma unroll
                for (int ni = 0; ni < 4; ++ni)
                    o[mi][ni] = fmaf(a[mi], b[ni], o[mi][ni]);
        }
    }

    // normalize + store (b, s, h*DK + dk) row-major
    const int b_ = bh >> 4;          // / H_
    const int h_ = bh & 15;
    #pragma unroll
    for (int mi = 0; mi < 4; ++mi) {
        const int i = ty * 4 + mi;
        const float inv_l = 1.0f / l_s[i];
        const int s_ = qb * 64 + i;
        size_t off = ((size_t)b_ * S_ + s_) * D_ + h_ * DK_ + tx * 4;
        *reinterpret_cast<float4*>(&attn[off]) =
            make_float4(o[mi][0] * inv_l, o[mi][1] * inv_l,
                        o[mi][2] * inv_l, o[mi][3] * inv_l);
    }
}

// ---------------------------------------------------------------------------
// Kernel 3: output projection (out = attn @ w_o^T), plain row-major store.
// ---------------------------------------------------------------------------
__global__ __launch_bounds__(256) void out_proj_kernel(
    const float* __restrict__ in, const float* __restrict__ w,
    float* __restrict__ out)
{
    __shared__ float As_t[32][68];
    __shared__ float Ws_t[32][68];

    const int tx = threadIdx.x;
    const int ty = threadIdx.y;
    const int tid = ty * 16 + tx;
    const int row0 = blockIdx.y * 64;
    const int col0 = blockIdx.x * 64;

    float acc[4][4] = {};

    for (int k0 = 0; k0 < D_; k0 += 32) {
        __syncthreads();
        #pragma unroll
        for (int t = 0; t < 2; ++t) {
            int idx = t * 256 + tid;
            int r  = idx >> 3;
            int c4 = idx & 7;
            float4 a = *reinterpret_cast<const float4*>(
                &in[(size_t)(row0 + r) * D_ + k0 + c4 * 4]);
            As_t[c4*4+0][r] = a.x; As_t[c4*4+1][r] = a.y;
            As_t[c4*4+2][r] = a.z; As_t[c4*4+3][r] = a.w;
            float4 b = *reinterpret_cast<const float4*>(
                &w[(size_t)(col0 + r) * D_ + k0 + c4 * 4]);
            Ws_t[c4*4+0][r] = b.x; Ws_t[c4*4+1][r] = b.y;
            Ws_t[c4*4+2][r] = b.z; Ws_t[c4*4+3][r] = b.w;
        }
        __syncthreads();
        #pragma unroll
        for (int kk = 0; kk < 32; ++kk) {
            float4 av = *reinterpret_cast<const float4*>(&As_t[kk][ty * 4]);
            float4 bv = *reinterpret_cast<const float4*>(&Ws_t[kk][tx * 4]);
            float a[4] = {av.x, av.y, av.z, av.w};
            float b[4] = {bv.x, bv.y, bv.z, bv.w};
            #pragma unroll
            for (int mi = 0; mi < 4; ++mi)
                #pragma unroll
                for (int ni = 0; ni < 4; ++ni)
                    acc[mi][ni] = fmaf(a[mi], b[ni], acc[mi][ni]);
        }
    }

    #pragma unroll
    for (int mi = 0; mi < 4; ++mi) {
        size_t off = (size_t)(row0 + ty * 4 + mi) * D_ + col0 + tx * 4;
        *reinterpret_cast<float4*>(&out[off]) =
            make_float4(acc[mi][0], acc[mi][1], acc[mi][2], acc[mi][3]);
    }
}

// ---------------------------------------------------------------------------
extern "C" void kernel_launch(void* const* d_in, const int* in_sizes, int n_in,
                              void* d_out, int out_size, void* d_ws, size_t ws_size,
                              hipStream_t stream) {
    const float* x       = (const float*)d_in[0];
    const float* w_q     = (const float*)d_in[1];
    const float* w_k     = (const float*)d_in[2];
    const float* w_v     = (const float*)d_in[3];
    const float* w_o     = (const float*)d_in[4];
    const float* sin_tab = (const float*)d_in[5];
    const float* cos_tab = (const float*)d_in[6];
    const int*   tpos    = (const int*)d_in[7];
    float* out = (float*)d_out;

    const size_t n_qkv = (size_t)B_ * H_ * S_ * DK_;   // 4,194,304 floats
    float* q_ws = (float*)d_ws;
    float* k_ws = q_ws + n_qkv;
    float* v_ws = k_ws + n_qkv;
    float* a_ws = v_ws + n_qkv;                        // total 64 MB of ws

    dim3 blk(16, 16);
    qkv_rope_kernel<<<dim3(D_ / 64, (B_ * S_) / 64, 3), blk, 0, stream>>>(
        x, w_q, w_k, w_v, q_ws, k_ws, v_ws, sin_tab, cos_tab, tpos);
    flash_attn_kernel<<<dim3(S_ / 64, B_ * H_), blk, 0, stream>>>(
        q_ws, k_ws, v_ws, a_ws);
    out_proj_kernel<<<dim3(D_ / 64, (B_ * S_) / 64), blk, 0, stream>>>(
        a_ws, w_o, out);
}

// Round 2
// 619.467 us; speedup vs baseline: 13.5547x; 13.5547x over previous
//
#include <hip/hip_runtime.h>
#include <hip/hip_bf16.h>
#include <cstdint>

#define B_ 2
#define S_ 2048
#define D_ 1024
#define H_ 16
#define DK_ 64
#define HALF_ 32   // DK/2

typedef short bf16x8 __attribute__((ext_vector_type(8)));
typedef float f32x4  __attribute__((ext_vector_type(4)));

static __device__ __forceinline__ unsigned short bfbits(float f) {
    __hip_bfloat16 h = __float2bfloat16(f);
    unsigned short u; __builtin_memcpy(&u, &h, 2); return u;
}
static __device__ __forceinline__ unsigned pack2bf(float a, float b) {
    return (unsigned)bfbits(a) | ((unsigned)bfbits(b) << 16);
}

// ---------------------------------------------------------------------------
// Kernel 1: QKV projection (out = x @ w^T) + RoPE epilogue, bf16 out (b,h,s,dk).
// Q additionally pre-scaled by 0.125 (=1/sqrt(DK), exact in bf16).
// ---------------------------------------------------------------------------
__global__ __launch_bounds__(256) void qkv_rope_kernel(
    const float* __restrict__ x,
    const float* __restrict__ w_q, const float* __restrict__ w_k,
    const float* __restrict__ w_v,
    __hip_bfloat16* __restrict__ q_out, __hip_bfloat16* __restrict__ k_out,
    __hip_bfloat16* __restrict__ v_out,
    const float* __restrict__ sin_tab, const float* __restrict__ cos_tab,
    const int* __restrict__ tpos)
{
    const int which = blockIdx.z;
    const float* __restrict__ w = (which == 0) ? w_q : (which == 1) ? w_k : w_v;
    __hip_bfloat16* __restrict__ out = (which == 0) ? q_out : (which == 1) ? k_out : v_out;

    __shared__ float As_t[32][68];
    __shared__ float Ws_t[32][68];

    const int tx = threadIdx.x;      // 0..15 -> n
    const int ty = threadIdx.y;      // 0..15 -> m
    const int tid = ty * 16 + tx;
    const int row0 = blockIdx.y * 64;   // M = B*S
    const int col0 = blockIdx.x * 64;   // N = D

    float acc[4][4] = {};

    for (int k0 = 0; k0 < D_; k0 += 32) {
        __syncthreads();
        #pragma unroll
        for (int t = 0; t < 2; ++t) {
            int idx = t * 256 + tid;
            int r  = idx >> 3;
            int c4 = idx & 7;
            float4 a = *reinterpret_cast<const float4*>(
                &x[(size_t)(row0 + r) * D_ + k0 + c4 * 4]);
            As_t[c4*4+0][r] = a.x; As_t[c4*4+1][r] = a.y;
            As_t[c4*4+2][r] = a.z; As_t[c4*4+3][r] = a.w;
            float4 b = *reinterpret_cast<const float4*>(
                &w[(size_t)(col0 + r) * D_ + k0 + c4 * 4]);
            Ws_t[c4*4+0][r] = b.x; Ws_t[c4*4+1][r] = b.y;
            Ws_t[c4*4+2][r] = b.z; Ws_t[c4*4+3][r] = b.w;
        }
        __syncthreads();
        #pragma unroll
        for (int kk = 0; kk < 32; ++kk) {
            float4 av = *reinterpret_cast<const float4*>(&As_t[kk][ty * 4]);
            float4 bv = *reinterpret_cast<const float4*>(&Ws_t[kk][tx * 4]);
            float a[4] = {av.x, av.y, av.z, av.w};
            float b[4] = {bv.x, bv.y, bv.z, bv.w};
            #pragma unroll
            for (int mi = 0; mi < 4; ++mi)
                #pragma unroll
                for (int ni = 0; ni < 4; ++ni)
                    acc[mi][ni] = fmaf(a[mi], b[ni], acc[mi][ni]);
        }
    }

    const int head = col0 >> 6;
    const int dk0  = tx * 4;
    const int f0   = dk0 >> 1;

    #pragma unroll
    for (int mi = 0; mi < 4; ++mi) {
        int gi = row0 + ty * 4 + mi;
        int b_ = gi >> 11;
        int s_ = gi & (S_ - 1);
        float v0 = acc[mi][0], v1 = acc[mi][1], v2 = acc[mi][2], v3 = acc[mi][3];
        if (which < 2) {
            int pos = tpos[gi];
            float sn0 = sin_tab[pos * HALF_ + f0];
            float cs0 = cos_tab[pos * HALF_ + f0];
            float sn1 = sin_tab[pos * HALF_ + f0 + 1];
            float cs1 = cos_tab[pos * HALF_ + f0 + 1];
            float e0 = cs0 * v0 - sn0 * v1;
            float o0 = sn0 * v0 + cs0 * v1;
            float e1 = cs1 * v2 - sn1 * v3;
            float o1 = sn1 * v2 + cs1 * v3;
            v0 = e0; v1 = o0; v2 = e1; v3 = o1;
        }
        if (which == 0) { v0 *= 0.125f; v1 *= 0.125f; v2 *= 0.125f; v3 *= 0.125f; }
        size_t off = (((size_t)b_ * H_ + head) * S_ + s_) * DK_ + dk0;
        ushort4 u = make_ushort4(bfbits(v0), bfbits(v1), bfbits(v2), bfbits(v3));
        *reinterpret_cast<ushort4*>(&out[off]) = u;
    }
}

// ---------------------------------------------------------------------------
// Kernel 2: causal flash attention with bf16 MFMA (16x16x32).
// Swapped products keep softmax lane-local:
//   S^T = K . Q^T  (per wave: 4 j-frags x 16 q-cols; lane holds 16 vals of ONE q-row)
//   O^T = V^T . P^T (rescale/normalize factors lane-local)
// All LDS tiles row-major 128B rows with XOR swizzle byte ^= (row&7)<<4;
// every fragment read is a conflict-free ds_read_b128.
// ---------------------------------------------------------------------------
__global__ __launch_bounds__(256) void flash_mfma_kernel(
    const __hip_bfloat16* __restrict__ q,   // (b,h,s,dk) pre-scaled by 0.125
    const __hip_bfloat16* __restrict__ k,
    const __hip_bfloat16* __restrict__ v,
    float* __restrict__ attn)               // (b,s,D)
{
    __shared__ __align__(16) unsigned char Qs [64 * 128];  // [row i][d*2]  swz
    __shared__ __align__(16) unsigned char Ks [64 * 128];  // [row j][d*2]  swz
    __shared__ __align__(16) unsigned char Vts[64 * 128];  // [row d][j*2]  swz (V transposed)
    __shared__ __align__(16) unsigned char Ps [4][16 * 128]; // per-wave [i][j*2] swz

    const int tid = threadIdx.x;
    const int w   = tid >> 6;        // wave 0..3  -> q rows [w*16, w*16+16)
    const int l   = tid & 63;
    const int g   = l >> 4;          // lane group 0..3
    const int i16 = l & 15;          // fragment col == q-row owned by this lane
    const int qb  = blockIdx.x;      // 0..31
    const int bh  = blockIdx.y;      // 0..31
    const size_t base = (size_t)bh * S_ * DK_;

    // ---- stage Q tile (row-major, swizzled), 2 x b128 per thread ----
    {
        const __hip_bfloat16* qbase = q + base + (size_t)qb * 64 * DK_;
        #pragma unroll
        for (int it = 0; it < 2; ++it) {
            int c = it * 256 + tid;          // 512 chunks of 16B
            int r = c >> 3, d8 = c & 7;
            float4 val = *reinterpret_cast<const float4*>(qbase + r * DK_ + d8 * 8);
            *reinterpret_cast<float4*>(Qs + r * 128 + ((d8 * 16) ^ ((r & 7) << 4))) = val;
        }
    }

    f32x4 o[4] = {};                 // O^T frags: df=0..3; lane col=i16, rows d
    float m_run = -1e30f, l_run = 0.0f;

    for (int kb = 0; kb <= qb; ++kb) {
        __syncthreads();             // previous tile's reads done (also covers Q staging)
        // ---- stage K (row-major) ----
        {
            const __hip_bfloat16* kbase = k + base + (size_t)kb * 64 * DK_;
            #pragma unroll
            for (int it = 0; it < 2; ++it) {
                int c = it * 256 + tid;
                int r = c >> 3, d8 = c & 7;
                float4 val = *reinterpret_cast<const float4*>(kbase + r * DK_ + d8 * 8);
                *reinterpret_cast<float4*>(Ks + r * 128 + ((d8 * 16) ^ ((r & 7) << 4))) = val;
            }
        }
        // ---- stage V transposed: Vt[d][j] ----
        {
            const __hip_bfloat16* vbase = v + base + (size_t)kb * 64 * DK_;
            #pragma unroll
            for (int it = 0; it < 2; ++it) {
                int j = tid & 63, d8 = it * 4 + (tid >> 6);
                float4 val = *reinterpret_cast<const float4*>(vbase + j * DK_ + d8 * 8);
                const unsigned short* u = reinterpret_cast<const unsigned short*>(&val);
                #pragma unroll
                for (int s = 0; s < 8; ++s) {
                    int d = d8 * 8 + s;
                    *reinterpret_cast<unsigned short*>(
                        Vts + d * 128 + ((j * 2) ^ ((d & 7) << 4))) = u[s];
                }
            }
        }
        __syncthreads();

        // ---- S^T = K . Q^T ----
        f32x4 s_acc[4] = {};
        #pragma unroll
        for (int kc = 0; kc < 2; ++kc) {     // d-chunks of 32
            const int bcol = kc * 64 + g * 16;
            bf16x8 bq = *reinterpret_cast<const bf16x8*>(
                Qs + (w * 16 + i16) * 128 + (bcol ^ ((i16 & 7) << 4)));
            #pragma unroll
            for (int jf = 0; jf < 4; ++jf) {
                int row = jf * 16 + i16;
                bf16x8 ak = *reinterpret_cast<const bf16x8*>(
                    Ks + row * 128 + (bcol ^ ((row & 7) << 4)));
                s_acc[jf] = __builtin_amdgcn_mfma_f32_16x16x32_bf16(ak, bq, s_acc[jf], 0, 0, 0);
            }
        }

        // ---- causal mask (diagonal tile only) ----
        if (kb == qb) {
            const int qg = w * 16 + i16;
            #pragma unroll
            for (int jf = 0; jf < 4; ++jf)
                #pragma unroll
                for (int r = 0; r < 4; ++r)
                    if (jf * 16 + g * 4 + r > qg) s_acc[jf][r] = -1e30f;
        }

        // ---- online softmax (row = i16; partners l^16, l^32 hold same row) ----
        float vmax = -1e30f;
        #pragma unroll
        for (int jf = 0; jf < 4; ++jf)
            #pragma unroll
            for (int r = 0; r < 4; ++r)
                vmax = fmaxf(vmax, s_acc[jf][r]);
        vmax = fmaxf(vmax, __shfl_xor(vmax, 16, 64));
        vmax = fmaxf(vmax, __shfl_xor(vmax, 32, 64));
        float m_new = fmaxf(m_run, vmax);
        float factor = __expf(m_run - m_new);
        m_run = m_new;

        float p[4][4];
        float psum = 0.0f;
        #pragma unroll
        for (int jf = 0; jf < 4; ++jf)
            #pragma unroll
            for (int r = 0; r < 4; ++r) {
                p[jf][r] = __expf(s_acc[jf][r] - m_new);
                psum += p[jf][r];
            }
        psum += __shfl_xor(psum, 16, 64);
        psum += __shfl_xor(psum, 32, 64);
        l_run = l_run * factor + psum;
        #pragma unroll
        for (int df = 0; df < 4; ++df)
            #pragma unroll
            for (int r = 0; r < 4; ++r)
                o[df][r] *= factor;

        // ---- pack P to bf16, write per-wave P_lds[i][j] (swizzled) ----
        unsigned char* pw = Ps[w];
        #pragma unroll
        for (int jf = 0; jf < 4; ++jf)
            #pragma unroll
            for (int r0 = 0; r0 < 4; r0 += 2) {
                unsigned pk = pack2bf(p[jf][r0], p[jf][r0 + 1]);
                int jj = jf * 16 + g * 4 + r0;
                *reinterpret_cast<unsigned*>(
                    pw + i16 * 128 + ((jj * 2) ^ ((i16 & 7) << 4))) = pk;
            }

        // ---- O^T += V^T . P^T ----  (wave-local P; lgkmcnt ordering only)
        #pragma unroll
        for (int jc = 0; jc < 2; ++jc) {     // j-chunks of 32
            const int bcol = jc * 64 + g * 16;
            bf16x8 bp = *reinterpret_cast<const bf16x8*>(
                pw + i16 * 128 + (bcol ^ ((i16 & 7) << 4)));
            #pragma unroll
            for (int df = 0; df < 4; ++df) {
                int row = df * 16 + i16;
                bf16x8 av = *reinterpret_cast<const bf16x8*>(
                    Vts + row * 128 + (bcol ^ ((row & 7) << 4)));
                o[df] = __builtin_amdgcn_mfma_f32_16x16x32_bf16(av, bp, o[df], 0, 0, 0);
            }
        }
    }

    // ---- normalize + store: O^T lane col = q-row i16, rows d = df*16+g*4+r ----
    const float inv_l = 1.0f / l_run;
    const int b_ = bh >> 4, h_ = bh & 15;
    const int sg = qb * 64 + w * 16 + i16;
    float* orow = attn + ((size_t)b_ * S_ + sg) * D_ + h_ * 64;
    #pragma unroll
    for (int df = 0; df < 4; ++df)
        #pragma unroll
        for (int r = 0; r < 4; ++r) {
            int d = df * 16 + g * 4 + r;
            orow[d] = o[df][r] * inv_l;
        }
}

// ---------------------------------------------------------------------------
// Kernel 3: output projection (out = attn @ w_o^T), fp32.
// ---------------------------------------------------------------------------
__global__ __launch_bounds__(256) void out_proj_kernel(
    const float* __restrict__ in, const float* __restrict__ w,
    float* __restrict__ out)
{
    __shared__ float As_t[32][68];
    __shared__ float Ws_t[32][68];

    const int tx = threadIdx.x;
    const int ty = threadIdx.y;
    const int tid = ty * 16 + tx;
    const int row0 = blockIdx.y * 64;
    const int col0 = blockIdx.x * 64;

    float acc[4][4] = {};

    for (int k0 = 0; k0 < D_; k0 += 32) {
        __syncthreads();
        #pragma unroll
        for (int t = 0; t < 2; ++t) {
            int idx = t * 256 + tid;
            int r  = idx >> 3;
            int c4 = idx & 7;
            float4 a = *reinterpret_cast<const float4*>(
                &in[(size_t)(row0 + r) * D_ + k0 + c4 * 4]);
            As_t[c4*4+0][r] = a.x; As_t[c4*4+1][r] = a.y;
            As_t[c4*4+2][r] = a.z; As_t[c4*4+3][r] = a.w;
            float4 b = *reinterpret_cast<const float4*>(
                &w[(size_t)(col0 + r) * D_ + k0 + c4 * 4]);
            Ws_t[c4*4+0][r] = b.x; Ws_t[c4*4+1][r] = b.y;
            Ws_t[c4*4+2][r] = b.z; Ws_t[c4*4+3][r] = b.w;
        }
        __syncthreads();
        #pragma unroll
        for (int kk = 0; kk < 32; ++kk) {
            float4 av = *reinterpret_cast<const float4*>(&As_t[kk][ty * 4]);
            float4 bv = *reinterpret_cast<const float4*>(&Ws_t[kk][tx * 4]);
            float a[4] = {av.x, av.y, av.z, av.w};
            float b[4] = {bv.x, bv.y, bv.z, bv.w};
            #pragma unroll
            for (int mi = 0; mi < 4; ++mi)
                #pragma unroll
                for (int ni = 0; ni < 4; ++ni)
                    acc[mi][ni] = fmaf(a[mi], b[ni], acc[mi][ni]);
        }
    }

    #pragma unroll
    for (int mi = 0; mi < 4; ++mi) {
        size_t off = (size_t)(row0 + ty * 4 + mi) * D_ + col0 + tx * 4;
        *reinterpret_cast<float4*>(&out[off]) =
            make_float4(acc[mi][0], acc[mi][1], acc[mi][2], acc[mi][3]);
    }
}

// ---------------------------------------------------------------------------
extern "C" void kernel_launch(void* const* d_in, const int* in_sizes, int n_in,
                              void* d_out, int out_size, void* d_ws, size_t ws_size,
                              hipStream_t stream) {
    const float* x       = (const float*)d_in[0];
    const float* w_q     = (const float*)d_in[1];
    const float* w_k     = (const float*)d_in[2];
    const float* w_v     = (const float*)d_in[3];
    const float* w_o     = (const float*)d_in[4];
    const float* sin_tab = (const float*)d_in[5];
    const float* cos_tab = (const float*)d_in[6];
    const int*   tpos    = (const int*)d_in[7];
    float* out = (float*)d_out;

    const size_t n_qkv = (size_t)B_ * H_ * S_ * DK_;        // 4,194,304
    __hip_bfloat16* q_ws = (__hip_bfloat16*)d_ws;           // 8 MB
    __hip_bfloat16* k_ws = q_ws + n_qkv;                    // 8 MB
    __hip_bfloat16* v_ws = k_ws + n_qkv;                    // 8 MB
    float* a_ws = (float*)(v_ws + n_qkv);                   // 16 MB

    dim3 blk(16, 16);
    qkv_rope_kernel<<<dim3(D_ / 64, (B_ * S_) / 64, 3), blk, 0, stream>>>(
        x, w_q, w_k, w_v, q_ws, k_ws, v_ws, sin_tab, cos_tab, tpos);
    flash_mfma_kernel<<<dim3(S_ / 64, B_ * H_), 256, 0, stream>>>(
        q_ws, k_ws, v_ws, a_ws);
    out_proj_kernel<<<dim3(D_ / 64, (B_ * S_) / 64), blk, 0, stream>>>(
        a_ws, w_o, out);
}

// Round 3
// 229.211 us; speedup vs baseline: 36.6330x; 2.7026x over previous
//
#include <hip/hip_runtime.h>
#include <hip/hip_bf16.h>
#include <cstdint>

#define B_ 2
#define S_ 2048
#define D_ 1024
#define H_ 16
#define DK_ 64
#define HALF_ 32   // DK/2

typedef short bf16x8 __attribute__((ext_vector_type(8)));
typedef float f32x4  __attribute__((ext_vector_type(4)));
typedef unsigned int u32;

static __device__ __forceinline__ unsigned short bfbits(float f) {
    __hip_bfloat16 h = __float2bfloat16(f);
    unsigned short u; __builtin_memcpy(&u, &h, 2); return u;
}
static __device__ __forceinline__ unsigned pack2bf(float a, float b) {
    return (unsigned)bfbits(a) | ((unsigned)bfbits(b) << 16);
}

// async 16B global->LDS (wave-uniform LDS base + lane*16; global addr per-lane)
static __device__ __forceinline__ void gload_lds16(const void* g, void* l) {
    __builtin_amdgcn_global_load_lds(
        (const __attribute__((address_space(1))) u32*)(uintptr_t)g,
        (__attribute__((address_space(3))) u32*)(uintptr_t)l,
        16, 0, 0);
}

// ---------------------------------------------------------------------------
// Kernel 0: fp32 -> bf16 conversion for x and the 4 weight matrices.
// ---------------------------------------------------------------------------
__global__ __launch_bounds__(256) void to_bf16_kernel(
    const float* __restrict__ x,
    const float* __restrict__ wq, const float* __restrict__ wk,
    const float* __restrict__ wv, const float* __restrict__ wo,
    __hip_bfloat16* __restrict__ xb,
    __hip_bfloat16* __restrict__ wqb, __hip_bfloat16* __restrict__ wkb,
    __hip_bfloat16* __restrict__ wvb, __hip_bfloat16* __restrict__ wob)
{
    const int seg = blockIdx.y;              // 0..3: x quarters; 4..7: weights
    const float* src;
    __hip_bfloat16* dst;
    size_t off = 0;
    if (seg < 4)       { src = x;  dst = xb;  off = (size_t)seg << 20; }
    else if (seg == 4) { src = wq; dst = wqb; }
    else if (seg == 5) { src = wk; dst = wkb; }
    else if (seg == 6) { src = wv; dst = wvb; }
    else               { src = wo; dst = wob; }
    size_t i = off + ((size_t)blockIdx.x * 256 + threadIdx.x) * 4;
    float4 v = *reinterpret_cast<const float4*>(src + i);
    ushort4 u = make_ushort4(bfbits(v.x), bfbits(v.y), bfbits(v.z), bfbits(v.w));
    *reinterpret_cast<ushort4*>(dst + i) = u;
}

// ---------------------------------------------------------------------------
// MFMA GEMM: C(M=4096, N=1024) = A(M,K=1024) @ W(N,K)^T, bf16 in, 16x16x32.
// 128x128 tile, BK=32, 4 waves (2x2, each 64x64 = 4x4 frags).
// LDS layout in 16B chunks (8 bf16 along K): chunk(row,kc) stored at slot
// row*4 + (kc ^ ((row>>1)&3)) -> 16-lane b128 reads hit all 8 bank positions.
// Staged with global_load_lds(16B): linear LDS dest, swizzle folded into the
// per-lane GLOBAL source address (m173 pattern).
// MODE 0: QKV. RoPE (+0.125 scale on Q) epilogue, bf16 out (b,h,s,dk), z=which.
// MODE 1: out-proj. fp32 row-major out.
// ---------------------------------------------------------------------------
template<int MODE>
__global__ __launch_bounds__(256) void mfma_gemm_kernel(
    const __hip_bfloat16* __restrict__ A,
    const __hip_bfloat16* __restrict__ Wq, const __hip_bfloat16* __restrict__ Wk,
    const __hip_bfloat16* __restrict__ Wv,
    __hip_bfloat16* __restrict__ out_q, __hip_bfloat16* __restrict__ out_k,
    __hip_bfloat16* __restrict__ out_v,
    float* __restrict__ out_f32,
    const float* __restrict__ sin_tab, const float* __restrict__ cos_tab,
    const int* __restrict__ tpos)
{
    constexpr int K = 1024;
    const int which = (MODE == 0) ? blockIdx.z : 3;
    const __hip_bfloat16* __restrict__ W =
        (MODE == 1) ? Wq : (which == 0 ? Wq : which == 1 ? Wk : Wv);

    __shared__ __align__(16) unsigned char As[128 * 4 * 16];  // 8 KB
    __shared__ __align__(16) unsigned char Bs[128 * 4 * 16];  // 8 KB

    const int tid = threadIdx.x;
    const int wid = tid >> 6;          // 0..3
    const int l   = tid & 63;
    const int g   = l >> 4;            // k-chunk group
    const int i16 = l & 15;
    const int wr  = wid >> 1, wc = wid & 1;
    const int row0 = blockIdx.y * 128;
    const int col0 = blockIdx.x * 128;

    const __hip_bfloat16* Abase = A + (size_t)row0 * K;
    const __hip_bfloat16* Wbase = W + (size_t)col0 * K;

    f32x4 acc[4][4];
    const f32x4 zero = {0.f, 0.f, 0.f, 0.f};
    #pragma unroll
    for (int mi = 0; mi < 4; ++mi)
        #pragma unroll
        for (int ni = 0; ni < 4; ++ni) acc[mi][ni] = zero;

    // read-side swizzled chunk byte offsets (row*4 + (g ^ ((row>>1)&3))) * 16
    int a_off[4], b_off[4];
    #pragma unroll
    for (int f = 0; f < 4; ++f) {
        int ra = wr * 64 + f * 16 + i16;
        a_off[f] = (ra * 4 + (g ^ ((ra >> 1) & 3))) * 16;
        int rb = wc * 64 + f * 16 + i16;
        b_off[f] = (rb * 4 + (g ^ ((rb >> 1) & 3))) * 16;
    }

    for (int k0 = 0; k0 < K; k0 += 32) {
        // stage A and B tiles (2 issues per wave per tile)
        #pragma unroll
        for (int it = 0; it < 2; ++it) {
            int c = it * 256 + wid * 64 + l;          // chunk 0..511
            int row = c >> 2;
            int kc = (c & 3) ^ ((row >> 1) & 3);      // inverse swizzle on source
            size_t goff = (size_t)row * K + k0 + kc * 8;
            gload_lds16(Abase + goff, As + (it * 256 + wid * 64) * 16);
            gload_lds16(Wbase + goff, Bs + (it * 256 + wid * 64) * 16);
        }
        __syncthreads();   // compiler emits vmcnt(0) drain before barrier

        bf16x8 af[4], bf[4];
        #pragma unroll
        for (int f = 0; f < 4; ++f) {
            af[f] = *reinterpret_cast<const bf16x8*>(As + a_off[f]);
            bf[f] = *reinterpret_cast<const bf16x8*>(Bs + b_off[f]);
        }
        #pragma unroll
        for (int mi = 0; mi < 4; ++mi)
            #pragma unroll
            for (int ni = 0; ni < 4; ++ni)
                acc[mi][ni] = __builtin_amdgcn_mfma_f32_16x16x32_bf16(
                    af[mi], bf[ni], acc[mi][ni], 0, 0, 0);
        __syncthreads();   // protect LDS before next stage
    }

    if (MODE == 0) {
        __hip_bfloat16* __restrict__ outp =
            which == 0 ? out_q : which == 1 ? out_k : out_v;
        const int head = (col0 >> 6) + wc;   // 2 heads per 128-col tile
        #pragma unroll
        for (int mi = 0; mi < 4; ++mi) {
            #pragma unroll
            for (int r = 0; r < 4; ++r) {
                const int gi = row0 + wr * 64 + mi * 16 + g * 4 + r;
                const int b_ = gi >> 11;
                const int s_ = gi & (S_ - 1);
                const int pos = tpos[gi];
                __hip_bfloat16* orow =
                    outp + (((size_t)b_ * H_ + head) * S_ + s_) * DK_;
                #pragma unroll
                for (int ni = 0; ni < 4; ++ni) {
                    float val = acc[mi][ni][r];
                    float other = __shfl_xor(val, 1, 64);
                    const int dk = ni * 16 + i16;
                    float res;
                    if (which < 2) {
                        const int f = dk >> 1;
                        float sn = sin_tab[pos * HALF_ + f];
                        float cs = cos_tab[pos * HALF_ + f];
                        res = (i16 & 1) ? fmaf(sn, other, cs * val)
                                        : (cs * val - sn * other);
                    } else {
                        res = val;
                    }
                    if (which == 0) res *= 0.125f;   // fold 1/sqrt(DK) into Q
                    orow[dk] = __float2bfloat16(res);
                }
            }
        }
    } else {
        #pragma unroll
        for (int mi = 0; mi < 4; ++mi) {
            #pragma unroll
            for (int r = 0; r < 4; ++r) {
                const int gi = row0 + wr * 64 + mi * 16 + g * 4 + r;
                float* orow = out_f32 + (size_t)gi * D_ + col0 + wc * 64;
                #pragma unroll
                for (int ni = 0; ni < 4; ++ni)
                    orow[ni * 16 + i16] = acc[mi][ni][r];
            }
        }
    }
}

// ---------------------------------------------------------------------------
// Kernel 2: causal flash attention with bf16 MFMA (16x16x32). Unchanged from
// round 2 except output is now bf16 (b,s,D) so the w_o GEMM reads bf16.
// ---------------------------------------------------------------------------
__global__ __launch_bounds__(256) void flash_mfma_kernel(
    const __hip_bfloat16* __restrict__ q,   // (b,h,s,dk) pre-scaled by 0.125
    const __hip_bfloat16* __restrict__ k,
    const __hip_bfloat16* __restrict__ v,
    __hip_bfloat16* __restrict__ attn)      // (b,s,D) bf16
{
    __shared__ __align__(16) unsigned char Qs [64 * 128];
    __shared__ __align__(16) unsigned char Ks [64 * 128];
    __shared__ __align__(16) unsigned char Vts[64 * 128];
    __shared__ __align__(16) unsigned char Ps [4][16 * 128];

    const int tid = threadIdx.x;
    const int w   = tid >> 6;
    const int l   = tid & 63;
    const int g   = l >> 4;
    const int i16 = l & 15;
    const int qb  = blockIdx.x;
    const int bh  = blockIdx.y;
    const size_t base = (size_t)bh * S_ * DK_;

    {
        const __hip_bfloat16* qbase = q + base + (size_t)qb * 64 * DK_;
        #pragma unroll
        for (int it = 0; it < 2; ++it) {
            int c = it * 256 + tid;
            int r = c >> 3, d8 = c & 7;
            float4 val = *reinterpret_cast<const float4*>(qbase + r * DK_ + d8 * 8);
            *reinterpret_cast<float4*>(Qs + r * 128 + ((d8 * 16) ^ ((r & 7) << 4))) = val;
        }
    }

    f32x4 o[4] = {};
    float m_run = -1e30f, l_run = 0.0f;

    for (int kb = 0; kb <= qb; ++kb) {
        __syncthreads();
        {
            const __hip_bfloat16* kbase = k + base + (size_t)kb * 64 * DK_;
            #pragma unroll
            for (int it = 0; it < 2; ++it) {
                int c = it * 256 + tid;
                int r = c >> 3, d8 = c & 7;
                float4 val = *reinterpret_cast<const float4*>(kbase + r * DK_ + d8 * 8);
                *reinterpret_cast<float4*>(Ks + r * 128 + ((d8 * 16) ^ ((r & 7) << 4))) = val;
            }
        }
        {
            const __hip_bfloat16* vbase = v + base + (size_t)kb * 64 * DK_;
            #pragma unroll
            for (int it = 0; it < 2; ++it) {
                int j = tid & 63, d8 = it * 4 + (tid >> 6);
                float4 val = *reinterpret_cast<const float4*>(vbase + j * DK_ + d8 * 8);
                const unsigned short* u = reinterpret_cast<const unsigned short*>(&val);
                #pragma unroll
                for (int s = 0; s < 8; ++s) {
                    int d = d8 * 8 + s;
                    *reinterpret_cast<unsigned short*>(
                        Vts + d * 128 + ((j * 2) ^ ((d & 7) << 4))) = u[s];
                }
            }
        }
        __syncthreads();

        f32x4 s_acc[4] = {};
        #pragma unroll
        for (int kc = 0; kc < 2; ++kc) {
            const int bcol = kc * 64 + g * 16;
            bf16x8 bq = *reinterpret_cast<const bf16x8*>(
                Qs + (w * 16 + i16) * 128 + (bcol ^ ((i16 & 7) << 4)));
            #pragma unroll
            for (int jf = 0; jf < 4; ++jf) {
                int row = jf * 16 + i16;
                bf16x8 ak = *reinterpret_cast<const bf16x8*>(
                    Ks + row * 128 + (bcol ^ ((row & 7) << 4)));
                s_acc[jf] = __builtin_amdgcn_mfma_f32_16x16x32_bf16(ak, bq, s_acc[jf], 0, 0, 0);
            }
        }

        if (kb == qb) {
            const int qg = w * 16 + i16;
            #pragma unroll
            for (int jf = 0; jf < 4; ++jf)
                #pragma unroll
                for (int r = 0; r < 4; ++r)
                    if (jf * 16 + g * 4 + r > qg) s_acc[jf][r] = -1e30f;
        }

        float vmax = -1e30f;
        #pragma unroll
        for (int jf = 0; jf < 4; ++jf)
            #pragma unroll
            for (int r = 0; r < 4; ++r)
                vmax = fmaxf(vmax, s_acc[jf][r]);
        vmax = fmaxf(vmax, __shfl_xor(vmax, 16, 64));
        vmax = fmaxf(vmax, __shfl_xor(vmax, 32, 64));
        float m_new = fmaxf(m_run, vmax);
        float factor = __expf(m_run - m_new);
        m_run = m_new;

        float p[4][4];
        float psum = 0.0f;
        #pragma unroll
        for (int jf = 0; jf < 4; ++jf)
            #pragma unroll
            for (int r = 0; r < 4; ++r) {
                p[jf][r] = __expf(s_acc[jf][r] - m_new);
                psum += p[jf][r];
            }
        psum += __shfl_xor(psum, 16, 64);
        psum += __shfl_xor(psum, 32, 64);
        l_run = l_run * factor + psum;
        #pragma unroll
        for (int df = 0; df < 4; ++df)
            #pragma unroll
            for (int r = 0; r < 4; ++r)
                o[df][r] *= factor;

        unsigned char* pw = Ps[w];
        #pragma unroll
        for (int jf = 0; jf < 4; ++jf)
            #pragma unroll
            for (int r0 = 0; r0 < 4; r0 += 2) {
                unsigned pk = pack2bf(p[jf][r0], p[jf][r0 + 1]);
                int jj = jf * 16 + g * 4 + r0;
                *reinterpret_cast<unsigned*>(
                    pw + i16 * 128 + ((jj * 2) ^ ((i16 & 7) << 4))) = pk;
            }

        #pragma unroll
        for (int jc = 0; jc < 2; ++jc) {
            const int bcol = jc * 64 + g * 16;
            bf16x8 bp = *reinterpret_cast<const bf16x8*>(
                pw + i16 * 128 + (bcol ^ ((i16 & 7) << 4)));
            #pragma unroll
            for (int df = 0; df < 4; ++df) {
                int row = df * 16 + i16;
                bf16x8 av = *reinterpret_cast<const bf16x8*>(
                    Vts + row * 128 + (bcol ^ ((row & 7) << 4)));
                o[df] = __builtin_amdgcn_mfma_f32_16x16x32_bf16(av, bp, o[df], 0, 0, 0);
            }
        }
    }

    const float inv_l = 1.0f / l_run;
    const int b_ = bh >> 4, h_ = bh & 15;
    const int sg = qb * 64 + w * 16 + i16;
    __hip_bfloat16* orow = attn + ((size_t)b_ * S_ + sg) * D_ + h_ * 64;
    #pragma unroll
    for (int df = 0; df < 4; ++df) {
        ushort4 u = make_ushort4(bfbits(o[df][0] * inv_l), bfbits(o[df][1] * inv_l),
                                 bfbits(o[df][2] * inv_l), bfbits(o[df][3] * inv_l));
        *reinterpret_cast<ushort4*>(orow + df * 16 + g * 4) = u;
    }
}

// ---------------------------------------------------------------------------
extern "C" void kernel_launch(void* const* d_in, const int* in_sizes, int n_in,
                              void* d_out, int out_size, void* d_ws, size_t ws_size,
                              hipStream_t stream) {
    const float* x       = (const float*)d_in[0];
    const float* w_q     = (const float*)d_in[1];
    const float* w_k     = (const float*)d_in[2];
    const float* w_v     = (const float*)d_in[3];
    const float* w_o     = (const float*)d_in[4];
    const float* sin_tab = (const float*)d_in[5];
    const float* cos_tab = (const float*)d_in[6];
    const int*   tpos    = (const int*)d_in[7];
    float* out = (float*)d_out;

    const size_t nM  = (size_t)B_ * S_ * D_;   // 4M elements
    const size_t nW  = (size_t)D_ * D_;        // 1M elements
    __hip_bfloat16* xb   = (__hip_bfloat16*)d_ws;   // 4M
    __hip_bfloat16* wqb  = xb  + nM;                // 1M
    __hip_bfloat16* wkb  = wqb + nW;
    __hip_bfloat16* wvb  = wkb + nW;
    __hip_bfloat16* wob  = wvb + nW;
    __hip_bfloat16* q_ws = wob + nW;                // 4M
    __hip_bfloat16* k_ws = q_ws + nM;
    __hip_bfloat16* v_ws = k_ws + nM;
    __hip_bfloat16* a_ws = v_ws + nM;               // 4M  (total 48 MB)

    to_bf16_kernel<<<dim3(1024, 8), 256, 0, stream>>>(
        x, w_q, w_k, w_v, w_o, xb, wqb, wkb, wvb, wob);
    mfma_gemm_kernel<0><<<dim3(D_ / 128, (B_ * S_) / 128, 3), 256, 0, stream>>>(
        xb, wqb, wkb, wvb, q_ws, k_ws, v_ws, nullptr, sin_tab, cos_tab, tpos);
    flash_mfma_kernel<<<dim3(S_ / 64, B_ * H_), 256, 0, stream>>>(
        q_ws, k_ws, v_ws, a_ws);
    mfma_gemm_kernel<1><<<dim3(D_ / 128, (B_ * S_) / 128, 1), 256, 0, stream>>>(
        a_ws, wob, nullptr, nullptr, nullptr, nullptr, nullptr, out,
        sin_tab, cos_tab, tpos);
}

// Round 4
// 167.397 us; speedup vs baseline: 50.1603x; 1.3693x over previous
//
#include <hip/hip_runtime.h>
#include <hip/hip_bf16.h>
#include <cstdint>

#define B_ 2
#define S_ 2048
#define D_ 1024
#define H_ 16
#define DK_ 64
#define HALF_ 32   // DK/2

typedef short bf16x8 __attribute__((ext_vector_type(8)));
typedef float f32x4  __attribute__((ext_vector_type(4)));
typedef unsigned int u32;

static __device__ __forceinline__ unsigned short bfbits(float f) {
    __hip_bfloat16 h = __float2bfloat16(f);
    unsigned short u; __builtin_memcpy(&u, &h, 2); return u;
}
static __device__ __forceinline__ unsigned pack2bf(float a, float b) {
    return (unsigned)bfbits(a) | ((unsigned)bfbits(b) << 16);
}

// async 16B global->LDS (wave-uniform LDS base + lane*16; global addr per-lane)
static __device__ __forceinline__ void gload_lds16(const void* g, void* l) {
    __builtin_amdgcn_global_load_lds(
        (const __attribute__((address_space(1))) u32*)(uintptr_t)g,
        (__attribute__((address_space(3))) u32*)(uintptr_t)l,
        16, 0, 0);
}

// ---------------------------------------------------------------------------
// Kernel 0: fp32 -> bf16 conversion for x and the 4 weight matrices.
// ---------------------------------------------------------------------------
__global__ __launch_bounds__(256) void to_bf16_kernel(
    const float* __restrict__ x,
    const float* __restrict__ wq, const float* __restrict__ wk,
    const float* __restrict__ wv, const float* __restrict__ wo,
    __hip_bfloat16* __restrict__ xb,
    __hip_bfloat16* __restrict__ wqb, __hip_bfloat16* __restrict__ wkb,
    __hip_bfloat16* __restrict__ wvb, __hip_bfloat16* __restrict__ wob)
{
    const int seg = blockIdx.y;              // 0..3: x quarters; 4..7: weights
    const float* src;
    __hip_bfloat16* dst;
    size_t off = 0;
    if (seg < 4)       { src = x;  dst = xb;  off = (size_t)seg << 20; }
    else if (seg == 4) { src = wq; dst = wqb; }
    else if (seg == 5) { src = wk; dst = wkb; }
    else if (seg == 6) { src = wv; dst = wvb; }
    else               { src = wo; dst = wob; }
    size_t i = off + ((size_t)blockIdx.x * 256 + threadIdx.x) * 4;
    float4 v = *reinterpret_cast<const float4*>(src + i);
    ushort4 u = make_ushort4(bfbits(v.x), bfbits(v.y), bfbits(v.z), bfbits(v.w));
    *reinterpret_cast<ushort4*>(dst + i) = u;
}

// ---------------------------------------------------------------------------
// MFMA GEMM (unchanged from round 3): C = A @ W^T, bf16 in, 16x16x32.
// MODE 0: QKV with RoPE epilogue -> bf16 (b,h,s,dk). MODE 1: out-proj -> fp32.
// ---------------------------------------------------------------------------
template<int MODE>
__global__ __launch_bounds__(256) void mfma_gemm_kernel(
    const __hip_bfloat16* __restrict__ A,
    const __hip_bfloat16* __restrict__ Wq, const __hip_bfloat16* __restrict__ Wk,
    const __hip_bfloat16* __restrict__ Wv,
    __hip_bfloat16* __restrict__ out_q, __hip_bfloat16* __restrict__ out_k,
    __hip_bfloat16* __restrict__ out_v,
    float* __restrict__ out_f32,
    const float* __restrict__ sin_tab, const float* __restrict__ cos_tab,
    const int* __restrict__ tpos)
{
    constexpr int K = 1024;
    const int which = (MODE == 0) ? blockIdx.z : 3;
    const __hip_bfloat16* __restrict__ W =
        (MODE == 1) ? Wq : (which == 0 ? Wq : which == 1 ? Wk : Wv);

    __shared__ __align__(16) unsigned char As[128 * 4 * 16];  // 8 KB
    __shared__ __align__(16) unsigned char Bs[128 * 4 * 16];  // 8 KB

    const int tid = threadIdx.x;
    const int wid = tid >> 6;
    const int l   = tid & 63;
    const int g   = l >> 4;
    const int i16 = l & 15;
    const int wr  = wid >> 1, wc = wid & 1;
    const int row0 = blockIdx.y * 128;
    const int col0 = blockIdx.x * 128;

    const __hip_bfloat16* Abase = A + (size_t)row0 * K;
    const __hip_bfloat16* Wbase = W + (size_t)col0 * K;

    f32x4 acc[4][4];
    const f32x4 zero = {0.f, 0.f, 0.f, 0.f};
    #pragma unroll
    for (int mi = 0; mi < 4; ++mi)
        #pragma unroll
        for (int ni = 0; ni < 4; ++ni) acc[mi][ni] = zero;

    int a_off[4], b_off[4];
    #pragma unroll
    for (int f = 0; f < 4; ++f) {
        int ra = wr * 64 + f * 16 + i16;
        a_off[f] = (ra * 4 + (g ^ ((ra >> 1) & 3))) * 16;
        int rb = wc * 64 + f * 16 + i16;
        b_off[f] = (rb * 4 + (g ^ ((rb >> 1) & 3))) * 16;
    }

    for (int k0 = 0; k0 < K; k0 += 32) {
        #pragma unroll
        for (int it = 0; it < 2; ++it) {
            int c = it * 256 + wid * 64 + l;
            int row = c >> 2;
            int kc = (c & 3) ^ ((row >> 1) & 3);
            size_t goff = (size_t)row * K + k0 + kc * 8;
            gload_lds16(Abase + goff, As + (it * 256 + wid * 64) * 16);
            gload_lds16(Wbase + goff, Bs + (it * 256 + wid * 64) * 16);
        }
        __syncthreads();

        bf16x8 af[4], bf[4];
        #pragma unroll
        for (int f = 0; f < 4; ++f) {
            af[f] = *reinterpret_cast<const bf16x8*>(As + a_off[f]);
            bf[f] = *reinterpret_cast<const bf16x8*>(Bs + b_off[f]);
        }
        #pragma unroll
        for (int mi = 0; mi < 4; ++mi)
            #pragma unroll
            for (int ni = 0; ni < 4; ++ni)
                acc[mi][ni] = __builtin_amdgcn_mfma_f32_16x16x32_bf16(
                    af[mi], bf[ni], acc[mi][ni], 0, 0, 0);
        __syncthreads();
    }

    if (MODE == 0) {
        __hip_bfloat16* __restrict__ outp =
            which == 0 ? out_q : which == 1 ? out_k : out_v;
        const int head = (col0 >> 6) + wc;
        #pragma unroll
        for (int mi = 0; mi < 4; ++mi) {
            #pragma unroll
            for (int r = 0; r < 4; ++r) {
                const int gi = row0 + wr * 64 + mi * 16 + g * 4 + r;
                const int b_ = gi >> 11;
                const int s_ = gi & (S_ - 1);
                const int pos = tpos[gi];
                __hip_bfloat16* orow =
                    outp + (((size_t)b_ * H_ + head) * S_ + s_) * DK_;
                #pragma unroll
                for (int ni = 0; ni < 4; ++ni) {
                    float val = acc[mi][ni][r];
                    float other = __shfl_xor(val, 1, 64);
                    const int dk = ni * 16 + i16;
                    float res;
                    if (which < 2) {
                        const int f = dk >> 1;
                        float sn = sin_tab[pos * HALF_ + f];
                        float cs = cos_tab[pos * HALF_ + f];
                        res = (i16 & 1) ? fmaf(sn, other, cs * val)
                                        : (cs * val - sn * other);
                    } else {
                        res = val;
                    }
                    if (which == 0) res *= 0.125f;
                    orow[dk] = __float2bfloat16(res);
                }
            }
        }
    } else {
        #pragma unroll
        for (int mi = 0; mi < 4; ++mi) {
            #pragma unroll
            for (int r = 0; r < 4; ++r) {
                const int gi = row0 + wr * 64 + mi * 16 + g * 4 + r;
                float* orow = out_f32 + (size_t)gi * D_ + col0 + wc * 64;
                #pragma unroll
                for (int ni = 0; ni < 4; ++ni)
                    orow[ni * 16 + i16] = acc[mi][ni][r];
            }
        }
    }
}

// ---------------------------------------------------------------------------
// Kernel 2 (v2): causal flash attention, bf16 MFMA 16x16x32.
//  - 8 waves, QBLK=128 (wave w owns q-rows w*16..w*16+15 of the q-block)
//  - causal pairing: block pid handles q-super-blocks {pid, 15-pid} -> every
//    block does exactly 34 KV tiles (uniform load across 256 blocks)
//  - Q hoisted to registers (2 x bf16x8 per lane), pre-scaled by 0.125
//  - K staged via global_load_lds (linear dest, inverse-swizzled source);
//    V^T staged via reg round-trip scatter; both double-buffered
//  - one __syncthreads per tile; prefetch next tile before compute (T14)
//  - all LDS tiles: 64 rows x 128B, chunk swizzle c ^= (row&7)
// ---------------------------------------------------------------------------
__global__ __launch_bounds__(512) void flash_mfma_kernel(
    const __hip_bfloat16* __restrict__ q,   // (b,h,s,dk), pre-scaled
    const __hip_bfloat16* __restrict__ k,
    const __hip_bfloat16* __restrict__ v,
    __hip_bfloat16* __restrict__ attn)      // (b,s,D) bf16
{
    __shared__ __align__(16) unsigned char Ks[2][64 * 128];  // 16 KB
    __shared__ __align__(16) unsigned char Vt[2][64 * 128];  // 16 KB
    __shared__ __align__(16) unsigned char Ps[8][16 * 128];  // 16 KB

    const int tid = threadIdx.x;
    const int w   = tid >> 6;        // 0..7
    const int l   = tid & 63;
    const int g   = l >> 4;
    const int i16 = l & 15;
    const int pid = blockIdx.x;      // 0..7
    const int bh  = blockIdx.y;      // 0..31
    const size_t base = (size_t)bh * S_ * DK_;
    const __hip_bfloat16* kb_ = k + base;
    const __hip_bfloat16* vb_ = v + base;

    // K staging geometry (constant): this thread fills chunk ci of the tile
    const int ci     = w * 64 + l;            // 0..511 (linear LDS 16B chunk)
    const int krow   = ci >> 3;               // 0..63
    const int kchunk = (ci & 7) ^ (krow & 7); // inverse swizzle on source
    const int ksrc   = krow * DK_ + kchunk * 8;
    unsigned char* const pw = &Ps[w][0];

    for (int pp = 0; pp < 2; ++pp) {
        const int qsb   = pp ? (15 - pid) : pid;
        const int qrow  = qsb * 128 + w * 16 + i16;   // this lane's q-row
        const int qbase = qsb * 128 + w * 16;         // wave's first q-row
        const int nt    = 2 * qsb + 2;

        // Q fragments in registers
        bf16x8 qf0, qf1;
        {
            const __hip_bfloat16* qp = q + base + (size_t)qrow * DK_ + g * 8;
            qf0 = *reinterpret_cast<const bf16x8*>(qp);
            qf1 = *reinterpret_cast<const bf16x8*>(qp + 32);
        }

        f32x4 o[4] = {};
        float m_run = -1e30f, l_run = 0.0f;

        // prologue: stage tile 0 into buffer 0
        gload_lds16(kb_ + ksrc, &Ks[0][0] + w * 1024);
        {
            float4 vv = *reinterpret_cast<const float4*>(vb_ + l * DK_ + w * 8);
            const unsigned short* u = reinterpret_cast<const unsigned short*>(&vv);
            #pragma unroll
            for (int s = 0; s < 8; ++s) {
                int d = w * 8 + s;
                *reinterpret_cast<unsigned short*>(&Vt[0][0] + d * 128 +
                    (((l >> 3) ^ (d & 7)) << 4) + (l & 7) * 2) = u[s];
            }
        }
        __syncthreads();

        for (int t = 0; t < nt; ++t) {
            const int cur = t & 1;
            const bool pre = (t + 1 < nt);
            float4 vv;
            if (pre) {   // issue next-tile loads early (hide under compute)
                gload_lds16(kb_ + (size_t)(t + 1) * 64 * DK_ + ksrc,
                            &Ks[cur ^ 1][0] + w * 1024);
                vv = *reinterpret_cast<const float4*>(
                    vb_ + (size_t)(t + 1) * 64 * DK_ + l * DK_ + w * 8);
            }

            if (t * 64 <= qbase + 15) {   // wave has unmasked rows in this tile
                // ---- S^T = K . Q^T ----
                f32x4 s_acc[4] = {};
                __builtin_amdgcn_s_setprio(1);
                #pragma unroll
                for (int jf = 0; jf < 4; ++jf) {
                    int row = jf * 16 + i16;
                    bf16x8 ak0 = *reinterpret_cast<const bf16x8*>(
                        &Ks[cur][0] + row * 128 + ((g ^ (row & 7)) << 4));
                    s_acc[jf] = __builtin_amdgcn_mfma_f32_16x16x32_bf16(
                        ak0, qf0, s_acc[jf], 0, 0, 0);
                    bf16x8 ak1 = *reinterpret_cast<const bf16x8*>(
                        &Ks[cur][0] + row * 128 + (((4 + g) ^ (row & 7)) << 4));
                    s_acc[jf] = __builtin_amdgcn_mfma_f32_16x16x32_bf16(
                        ak1, qf1, s_acc[jf], 0, 0, 0);
                }
                __builtin_amdgcn_s_setprio(0);

                // ---- causal mask (only near the diagonal) ----
                if (t * 64 + 63 > qbase) {
                    #pragma unroll
                    for (int jf = 0; jf < 4; ++jf)
                        #pragma unroll
                        for (int r = 0; r < 4; ++r)
                            if (t * 64 + jf * 16 + g * 4 + r > qrow)
                                s_acc[jf][r] = -1e30f;
                }

                // ---- online softmax (partners l^16, l^32 share q-row) ----
                float vmax = -1e30f;
                #pragma unroll
                for (int jf = 0; jf < 4; ++jf)
                    #pragma unroll
                    for (int r = 0; r < 4; ++r)
                        vmax = fmaxf(vmax, s_acc[jf][r]);
                vmax = fmaxf(vmax, __shfl_xor(vmax, 16, 64));
                vmax = fmaxf(vmax, __shfl_xor(vmax, 32, 64));
                float m_new = fmaxf(m_run, vmax);
                float factor = __expf(m_run - m_new);
                m_run = m_new;

                float p[4][4];
                float psum = 0.0f;
                #pragma unroll
                for (int jf = 0; jf < 4; ++jf)
                    #pragma unroll
                    for (int r = 0; r < 4; ++r) {
                        p[jf][r] = __expf(s_acc[jf][r] - m_new);
                        psum += p[jf][r];
                    }
                psum += __shfl_xor(psum, 16, 64);
                psum += __shfl_xor(psum, 32, 64);
                l_run = l_run * factor + psum;
                #pragma unroll
                for (int df = 0; df < 4; ++df)
                    #pragma unroll
                    for (int r = 0; r < 4; ++r)
                        o[df][r] *= factor;

                // ---- pack P -> bf16, wave-local LDS (swizzled) ----
                #pragma unroll
                for (int jf = 0; jf < 4; ++jf)
                    #pragma unroll
                    for (int r0 = 0; r0 < 4; r0 += 2) {
                        unsigned pk = pack2bf(p[jf][r0], p[jf][r0 + 1]);
                        int jj = jf * 16 + g * 4 + r0;
                        *reinterpret_cast<unsigned*>(pw + i16 * 128 +
                            ((jj * 2) ^ ((i16 & 7) << 4))) = pk;
                    }

                // ---- O^T += V^T . P^T ----
                __builtin_amdgcn_s_setprio(1);
                #pragma unroll
                for (int jc = 0; jc < 2; ++jc) {
                    bf16x8 bp = *reinterpret_cast<const bf16x8*>(pw + i16 * 128 +
                        (((jc * 4 + g) ^ (i16 & 7)) << 4));
                    #pragma unroll
                    for (int df = 0; df < 4; ++df) {
                        int row = df * 16 + i16;
                        bf16x8 av = *reinterpret_cast<const bf16x8*>(
                            &Vt[cur][0] + row * 128 +
                            (((jc * 4 + g) ^ (row & 7)) << 4));
                        o[df] = __builtin_amdgcn_mfma_f32_16x16x32_bf16(
                            av, bp, o[df], 0, 0, 0);
                    }
                }
                __builtin_amdgcn_s_setprio(0);
            }

            if (pre) {   // scatter-write next V^T after compute
                const unsigned short* u = reinterpret_cast<const unsigned short*>(&vv);
                unsigned char* vtb = &Vt[cur ^ 1][0];
                #pragma unroll
                for (int s = 0; s < 8; ++s) {
                    int d = w * 8 + s;
                    *reinterpret_cast<unsigned short*>(vtb + d * 128 +
                        (((l >> 3) ^ (d & 7)) << 4) + (l & 7) * 2) = u[s];
                }
            }
            __syncthreads();   // drains gload_lds (vmcnt) + LDS writes
        }

        // ---- normalize + store ----
        const float inv_l = 1.0f / l_run;
        const int b_ = bh >> 4, h_ = bh & 15;
        __hip_bfloat16* orow = attn + ((size_t)b_ * S_ + qrow) * D_ + h_ * 64;
        #pragma unroll
        for (int df = 0; df < 4; ++df) {
            ushort4 uo = make_ushort4(
                bfbits(o[df][0] * inv_l), bfbits(o[df][1] * inv_l),
                bfbits(o[df][2] * inv_l), bfbits(o[df][3] * inv_l));
            *reinterpret_cast<ushort4*>(orow + df * 16 + g * 4) = uo;
        }
    }
}

// ---------------------------------------------------------------------------
extern "C" void kernel_launch(void* const* d_in, const int* in_sizes, int n_in,
                              void* d_out, int out_size, void* d_ws, size_t ws_size,
                              hipStream_t stream) {
    const float* x       = (const float*)d_in[0];
    const float* w_q     = (const float*)d_in[1];
    const float* w_k     = (const float*)d_in[2];
    const float* w_v     = (const float*)d_in[3];
    const float* w_o     = (const float*)d_in[4];
    const float* sin_tab = (const float*)d_in[5];
    const float* cos_tab = (const float*)d_in[6];
    const int*   tpos    = (const int*)d_in[7];
    float* out = (float*)d_out;

    const size_t nM  = (size_t)B_ * S_ * D_;
    const size_t nW  = (size_t)D_ * D_;
    __hip_bfloat16* xb   = (__hip_bfloat16*)d_ws;
    __hip_bfloat16* wqb  = xb  + nM;
    __hip_bfloat16* wkb  = wqb + nW;
    __hip_bfloat16* wvb  = wkb + nW;
    __hip_bfloat16* wob  = wvb + nW;
    __hip_bfloat16* q_ws = wob + nW;
    __hip_bfloat16* k_ws = q_ws + nM;
    __hip_bfloat16* v_ws = k_ws + nM;
    __hip_bfloat16* a_ws = v_ws + nM;

    to_bf16_kernel<<<dim3(1024, 8), 256, 0, stream>>>(
        x, w_q, w_k, w_v, w_o, xb, wqb, wkb, wvb, wob);
    mfma_gemm_kernel<0><<<dim3(D_ / 128, (B_ * S_) / 128, 3), 256, 0, stream>>>(
        xb, wqb, wkb, wvb, q_ws, k_ws, v_ws, nullptr, sin_tab, cos_tab, tpos);
    flash_mfma_kernel<<<dim3(8, B_ * H_), 512, 0, stream>>>(
        q_ws, k_ws, v_ws, a_ws);
    mfma_gemm_kernel<1><<<dim3(D_ / 128, (B_ * S_) / 128, 1), 256, 0, stream>>>(
        a_ws, wob, nullptr, nullptr, nullptr, nullptr, nullptr, out,
        sin_tab, cos_tab, tpos);
}

// Round 5
// 139.983 us; speedup vs baseline: 59.9834x; 1.1958x over previous
//
#include <hip/hip_runtime.h>
#include <hip/hip_bf16.h>
#include <cstdint>

#define B_ 2
#define S_ 2048
#define D_ 1024
#define H_ 16
#define DK_ 64
#define HALF_ 32   // DK/2

typedef short bf16x8 __attribute__((ext_vector_type(8)));
typedef float f32x4  __attribute__((ext_vector_type(4)));
typedef unsigned int u32;

static __device__ __forceinline__ unsigned short bfbits(float f) {
    __hip_bfloat16 h = __float2bfloat16(f);
    unsigned short u; __builtin_memcpy(&u, &h, 2); return u;
}
static __device__ __forceinline__ unsigned pack2bf(float a, float b) {
    return (unsigned)bfbits(a) | ((unsigned)bfbits(b) << 16);
}

// async 16B global->LDS (wave-uniform LDS base + lane*16; global addr per-lane)
static __device__ __forceinline__ void gload_lds16(const void* g, void* l) {
    __builtin_amdgcn_global_load_lds(
        (const __attribute__((address_space(1))) u32*)(uintptr_t)g,
        (__attribute__((address_space(3))) u32*)(uintptr_t)l,
        16, 0, 0);
}

// ---------------------------------------------------------------------------
// Kernel 0: fp32 -> bf16 conversion (x + 4 weights) and packed (cos,sin) table.
// ---------------------------------------------------------------------------
__global__ __launch_bounds__(256) void to_bf16_kernel(
    const float* __restrict__ x,
    const float* __restrict__ wq, const float* __restrict__ wk,
    const float* __restrict__ wv, const float* __restrict__ wo,
    const float* __restrict__ sin_tab, const float* __restrict__ cos_tab,
    __hip_bfloat16* __restrict__ xb,
    __hip_bfloat16* __restrict__ wqb, __hip_bfloat16* __restrict__ wkb,
    __hip_bfloat16* __restrict__ wvb, __hip_bfloat16* __restrict__ wob,
    float2* __restrict__ sctab)
{
    const int seg = blockIdx.y;   // 0..3 x quarters; 4..7 weights; 8 sincos
    if (seg == 8) {
        if (blockIdx.x >= 64) return;     // 65536 entries / 4 per thread
        size_t i = ((size_t)blockIdx.x * 256 + threadIdx.x) * 4;
        float4 c = *reinterpret_cast<const float4*>(cos_tab + i);
        float4 s = *reinterpret_cast<const float4*>(sin_tab + i);
        float4* dst = reinterpret_cast<float4*>(sctab + i);
        dst[0] = make_float4(c.x, s.x, c.y, s.y);
        dst[1] = make_float4(c.z, s.z, c.w, s.w);
        return;
    }
    const float* src;
    __hip_bfloat16* dst;
    size_t off = 0;
    if (seg < 4)       { src = x;  dst = xb;  off = (size_t)seg << 20; }
    else if (seg == 4) { src = wq; dst = wqb; }
    else if (seg == 5) { src = wk; dst = wkb; }
    else if (seg == 6) { src = wv; dst = wvb; }
    else               { src = wo; dst = wob; }
    size_t i = off + ((size_t)blockIdx.x * 256 + threadIdx.x) * 4;
    float4 v = *reinterpret_cast<const float4*>(src + i);
    ushort4 u = make_ushort4(bfbits(v.x), bfbits(v.y), bfbits(v.z), bfbits(v.w));
    *reinterpret_cast<ushort4*>(dst + i) = u;
}

// ---------------------------------------------------------------------------
// MFMA GEMM v2: C(4096, 1024) = A @ W^T, bf16 in, 16x16x32, 128x128 tile,
// BK=32, 4 waves.
//  - 1-D grid (256 blocks/which) with XCD-chunked swizzle: each XCD gets 4
//    contiguous row-tiles x all 8 col-tiles -> A-panel L2 reuse (T1).
//  - Double-buffered LDS, 2-phase loop (T3-minimum): stage(t+1) issued
//    before compute(t), one __syncthreads per K-step.
//  - LDS chunk swizzle (row*4 + (kc ^ ((row>>1)&3))), inverse folded into
//    the global source address (rule 21).
// MODE 0: QKV + RoPE epilogue (packed sctab), bf16 out (b,h,s,dk), z=which.
// MODE 1: out-proj, fp32 row-major out.
// ---------------------------------------------------------------------------
template<int MODE>
__global__ __launch_bounds__(256) void mfma_gemm_kernel(
    const __hip_bfloat16* __restrict__ A,
    const __hip_bfloat16* __restrict__ Wq, const __hip_bfloat16* __restrict__ Wk,
    const __hip_bfloat16* __restrict__ Wv,
    __hip_bfloat16* __restrict__ out_q, __hip_bfloat16* __restrict__ out_k,
    __hip_bfloat16* __restrict__ out_v,
    float* __restrict__ out_f32,
    const float2* __restrict__ sctab,
    const int* __restrict__ tpos)
{
    constexpr int K = 1024;
    const int which = (MODE == 0) ? blockIdx.z : 3;
    const __hip_bfloat16* __restrict__ W =
        (MODE == 1) ? Wq : (which == 0 ? Wq : which == 1 ? Wk : Wv);

    __shared__ __align__(16) unsigned char As[2][128 * 4 * 16];  // 2 x 8 KB
    __shared__ __align__(16) unsigned char Bs[2][128 * 4 * 16];  // 2 x 8 KB

    const int tid = threadIdx.x;
    const int wid = tid >> 6;
    const int l   = tid & 63;
    const int g   = l >> 4;
    const int i16 = l & 15;
    const int wr  = wid >> 1, wc = wid & 1;

    // XCD-chunked bijective swizzle: 256 blocks = 8 xcd * (4 rows x 8 cols)
    const int wg   = blockIdx.x;
    const int tile = (wg & 7) * 32 + (wg >> 3);
    const int row0 = (tile >> 3) * 128;
    const int col0 = (tile & 7) * 128;

    const __hip_bfloat16* Abase = A + (size_t)row0 * K;
    const __hip_bfloat16* Wbase = W + (size_t)col0 * K;

    f32x4 acc[4][4];
    const f32x4 zero = {0.f, 0.f, 0.f, 0.f};
    #pragma unroll
    for (int mi = 0; mi < 4; ++mi)
        #pragma unroll
        for (int ni = 0; ni < 4; ++ni) acc[mi][ni] = zero;

    // fragment read offsets (swizzled)
    int a_off[4], b_off[4];
    #pragma unroll
    for (int f = 0; f < 4; ++f) {
        int ra = wr * 64 + f * 16 + i16;
        a_off[f] = (ra * 4 + (g ^ ((ra >> 1) & 3))) * 16;
        int rb = wc * 64 + f * 16 + i16;
        b_off[f] = (rb * 4 + (g ^ ((rb >> 1) & 3))) * 16;
    }

    // staging geometry: thread fills chunks {wid*64+l, 256+wid*64+l}
    int st_goff[2], st_loff[2];
    #pragma unroll
    for (int it = 0; it < 2; ++it) {
        int c = it * 256 + wid * 64 + l;
        int row = c >> 2;
        int kc = (c & 3) ^ ((row >> 1) & 3);       // inverse swizzle on source
        st_goff[it] = row * K + kc * 8;
        st_loff[it] = (it * 256 + wid * 64) * 16;  // linear dest (wave-uniform base)
    }

    // prologue: stage k0=0 into buffer 0
    #pragma unroll
    for (int it = 0; it < 2; ++it) {
        gload_lds16(Abase + st_goff[it], &As[0][0] + st_loff[it]);
        gload_lds16(Wbase + st_goff[it], &Bs[0][0] + st_loff[it]);
    }
    __syncthreads();

    for (int t = 0; t < K / 32; ++t) {
        const int cur = t & 1;
        if (t + 1 < K / 32) {         // issue next-tile loads BEFORE compute
            const int k1 = (t + 1) * 32;
            #pragma unroll
            for (int it = 0; it < 2; ++it) {
                gload_lds16(Abase + k1 + st_goff[it], &As[cur ^ 1][0] + st_loff[it]);
                gload_lds16(Wbase + k1 + st_goff[it], &Bs[cur ^ 1][0] + st_loff[it]);
            }
        }
        bf16x8 af[4], bfr[4];
        #pragma unroll
        for (int f = 0; f < 4; ++f) {
            af[f]  = *reinterpret_cast<const bf16x8*>(&As[cur][0] + a_off[f]);
            bfr[f] = *reinterpret_cast<const bf16x8*>(&Bs[cur][0] + b_off[f]);
        }
        #pragma unroll
        for (int mi = 0; mi < 4; ++mi)
            #pragma unroll
            for (int ni = 0; ni < 4; ++ni)
                acc[mi][ni] = __builtin_amdgcn_mfma_f32_16x16x32_bf16(
                    af[mi], bfr[ni], acc[mi][ni], 0, 0, 0);
        __syncthreads();   // drains vmcnt (stage t+1 done) + all LDS reads done
    }

    if (MODE == 0) {
        __hip_bfloat16* __restrict__ outp =
            which == 0 ? out_q : which == 1 ? out_k : out_v;
        const int head = (col0 >> 6) + wc;
        #pragma unroll
        for (int mi = 0; mi < 4; ++mi) {
            #pragma unroll
            for (int r = 0; r < 4; ++r) {
                const int gi = row0 + wr * 64 + mi * 16 + g * 4 + r;
                const int b_ = gi >> 11;
                const int s_ = gi & (S_ - 1);
                const int pos = tpos[gi];
                const float2* sc = sctab + pos * HALF_;
                __hip_bfloat16* orow =
                    outp + (((size_t)b_ * H_ + head) * S_ + s_) * DK_;
                #pragma unroll
                for (int ni = 0; ni < 4; ++ni) {
                    float val = acc[mi][ni][r];
                    float other = __shfl_xor(val, 1, 64);
                    const int dk = ni * 16 + i16;
                    float res;
                    if (which < 2) {
                        float2 cs = sc[ni * 8 + (i16 >> 1)];
                        res = (i16 & 1) ? fmaf(cs.y, other, cs.x * val)
                                        : (cs.x * val - cs.y * other);
                    } else {
                        res = val;
                    }
                    if (which == 0) res *= 0.125f;
                    orow[dk] = __float2bfloat16(res);
                }
            }
        }
    } else {
        #pragma unroll
        for (int mi = 0; mi < 4; ++mi) {
            #pragma unroll
            for (int r = 0; r < 4; ++r) {
                const int gi = row0 + wr * 64 + mi * 16 + g * 4 + r;
                float* orow = out_f32 + (size_t)gi * D_ + col0 + wc * 64;
                #pragma unroll
                for (int ni = 0; ni < 4; ++ni)
                    orow[ni * 16 + i16] = acc[mi][ni][r];
            }
        }
    }
}

// ---------------------------------------------------------------------------
// Kernel 2: causal flash attention, bf16 MFMA 16x16x32 (unchanged, round 4).
// ---------------------------------------------------------------------------
__global__ __launch_bounds__(512) void flash_mfma_kernel(
    const __hip_bfloat16* __restrict__ q,   // (b,h,s,dk), pre-scaled
    const __hip_bfloat16* __restrict__ k,
    const __hip_bfloat16* __restrict__ v,
    __hip_bfloat16* __restrict__ attn)      // (b,s,D) bf16
{
    __shared__ __align__(16) unsigned char Ks[2][64 * 128];
    __shared__ __align__(16) unsigned char Vt[2][64 * 128];
    __shared__ __align__(16) unsigned char Ps[8][16 * 128];

    const int tid = threadIdx.x;
    const int w   = tid >> 6;
    const int l   = tid & 63;
    const int g   = l >> 4;
    const int i16 = l & 15;
    const int pid = blockIdx.x;
    const int bh  = blockIdx.y;
    const size_t base = (size_t)bh * S_ * DK_;
    const __hip_bfloat16* kb_ = k + base;
    const __hip_bfloat16* vb_ = v + base;

    const int ci     = w * 64 + l;
    const int krow   = ci >> 3;
    const int kchunk = (ci & 7) ^ (krow & 7);
    const int ksrc   = krow * DK_ + kchunk * 8;
    unsigned char* const pw = &Ps[w][0];

    for (int pp = 0; pp < 2; ++pp) {
        const int qsb   = pp ? (15 - pid) : pid;
        const int qrow  = qsb * 128 + w * 16 + i16;
        const int qbase = qsb * 128 + w * 16;
        const int nt    = 2 * qsb + 2;

        bf16x8 qf0, qf1;
        {
            const __hip_bfloat16* qp = q + base + (size_t)qrow * DK_ + g * 8;
            qf0 = *reinterpret_cast<const bf16x8*>(qp);
            qf1 = *reinterpret_cast<const bf16x8*>(qp + 32);
        }

        f32x4 o[4] = {};
        float m_run = -1e30f, l_run = 0.0f;

        gload_lds16(kb_ + ksrc, &Ks[0][0] + w * 1024);
        {
            float4 vv = *reinterpret_cast<const float4*>(vb_ + l * DK_ + w * 8);
            const unsigned short* u = reinterpret_cast<const unsigned short*>(&vv);
            #pragma unroll
            for (int s = 0; s < 8; ++s) {
                int d = w * 8 + s;
                *reinterpret_cast<unsigned short*>(&Vt[0][0] + d * 128 +
                    (((l >> 3) ^ (d & 7)) << 4) + (l & 7) * 2) = u[s];
            }
        }
        __syncthreads();

        for (int t = 0; t < nt; ++t) {
            const int cur = t & 1;
            const bool pre = (t + 1 < nt);
            float4 vv;
            if (pre) {
                gload_lds16(kb_ + (size_t)(t + 1) * 64 * DK_ + ksrc,
                            &Ks[cur ^ 1][0] + w * 1024);
                vv = *reinterpret_cast<const float4*>(
                    vb_ + (size_t)(t + 1) * 64 * DK_ + l * DK_ + w * 8);
            }

            if (t * 64 <= qbase + 15) {
                f32x4 s_acc[4] = {};
                __builtin_amdgcn_s_setprio(1);
                #pragma unroll
                for (int jf = 0; jf < 4; ++jf) {
                    int row = jf * 16 + i16;
                    bf16x8 ak0 = *reinterpret_cast<const bf16x8*>(
                        &Ks[cur][0] + row * 128 + ((g ^ (row & 7)) << 4));
                    s_acc[jf] = __builtin_amdgcn_mfma_f32_16x16x32_bf16(
                        ak0, qf0, s_acc[jf], 0, 0, 0);
                    bf16x8 ak1 = *reinterpret_cast<const bf16x8*>(
                        &Ks[cur][0] + row * 128 + (((4 + g) ^ (row & 7)) << 4));
                    s_acc[jf] = __builtin_amdgcn_mfma_f32_16x16x32_bf16(
                        ak1, qf1, s_acc[jf], 0, 0, 0);
                }
                __builtin_amdgcn_s_setprio(0);

                if (t * 64 + 63 > qbase) {
                    #pragma unroll
                    for (int jf = 0; jf < 4; ++jf)
                        #pragma unroll
                        for (int r = 0; r < 4; ++r)
                            if (t * 64 + jf * 16 + g * 4 + r > qrow)
                                s_acc[jf][r] = -1e30f;
                }

                float vmax = -1e30f;
                #pragma unroll
                for (int jf = 0; jf < 4; ++jf)
                    #pragma unroll
                    for (int r = 0; r < 4; ++r)
                        vmax = fmaxf(vmax, s_acc[jf][r]);
                vmax = fmaxf(vmax, __shfl_xor(vmax, 16, 64));
                vmax = fmaxf(vmax, __shfl_xor(vmax, 32, 64));
                float m_new = fmaxf(m_run, vmax);
                float factor = __expf(m_run - m_new);
                m_run = m_new;

                float p[4][4];
                float psum = 0.0f;
                #pragma unroll
                for (int jf = 0; jf < 4; ++jf)
                    #pragma unroll
                    for (int r = 0; r < 4; ++r) {
                        p[jf][r] = __expf(s_acc[jf][r] - m_new);
                        psum += p[jf][r];
                    }
                psum += __shfl_xor(psum, 16, 64);
                psum += __shfl_xor(psum, 32, 64);
                l_run = l_run * factor + psum;
                #pragma unroll
                for (int df = 0; df < 4; ++df)
                    #pragma unroll
                    for (int r = 0; r < 4; ++r)
                        o[df][r] *= factor;

                #pragma unroll
                for (int jf = 0; jf < 4; ++jf)
                    #pragma unroll
                    for (int r0 = 0; r0 < 4; r0 += 2) {
                        unsigned pk = pack2bf(p[jf][r0], p[jf][r0 + 1]);
                        int jj = jf * 16 + g * 4 + r0;
                        *reinterpret_cast<unsigned*>(pw + i16 * 128 +
                            ((jj * 2) ^ ((i16 & 7) << 4))) = pk;
                    }

                __builtin_amdgcn_s_setprio(1);
                #pragma unroll
                for (int jc = 0; jc < 2; ++jc) {
                    bf16x8 bp = *reinterpret_cast<const bf16x8*>(pw + i16 * 128 +
                        (((jc * 4 + g) ^ (i16 & 7)) << 4));
                    #pragma unroll
                    for (int df = 0; df < 4; ++df) {
                        int row = df * 16 + i16;
                        bf16x8 av = *reinterpret_cast<const bf16x8*>(
                            &Vt[cur][0] + row * 128 +
                            (((jc * 4 + g) ^ (row & 7)) << 4));
                        o[df] = __builtin_amdgcn_mfma_f32_16x16x32_bf16(
                            av, bp, o[df], 0, 0, 0);
                    }
                }
                __builtin_amdgcn_s_setprio(0);
            }

            if (pre) {
                const unsigned short* u = reinterpret_cast<const unsigned short*>(&vv);
                unsigned char* vtb = &Vt[cur ^ 1][0];
                #pragma unroll
                for (int s = 0; s < 8; ++s) {
                    int d = w * 8 + s;
                    *reinterpret_cast<unsigned short*>(vtb + d * 128 +
                        (((l >> 3) ^ (d & 7)) << 4) + (l & 7) * 2) = u[s];
                }
            }
            __syncthreads();
        }

        const float inv_l = 1.0f / l_run;
        const int b_ = bh >> 4, h_ = bh & 15;
        __hip_bfloat16* orow = attn + ((size_t)b_ * S_ + qrow) * D_ + h_ * 64;
        #pragma unroll
        for (int df = 0; df < 4; ++df) {
            ushort4 uo = make_ushort4(
                bfbits(o[df][0] * inv_l), bfbits(o[df][1] * inv_l),
                bfbits(o[df][2] * inv_l), bfbits(o[df][3] * inv_l));
            *reinterpret_cast<ushort4*>(orow + df * 16 + g * 4) = uo;
        }
    }
}

// ---------------------------------------------------------------------------
extern "C" void kernel_launch(void* const* d_in, const int* in_sizes, int n_in,
                              void* d_out, int out_size, void* d_ws, size_t ws_size,
                              hipStream_t stream) {
    const float* x       = (const float*)d_in[0];
    const float* w_q     = (const float*)d_in[1];
    const float* w_k     = (const float*)d_in[2];
    const float* w_v     = (const float*)d_in[3];
    const float* w_o     = (const float*)d_in[4];
    const float* sin_tab = (const float*)d_in[5];
    const float* cos_tab = (const float*)d_in[6];
    const int*   tpos    = (const int*)d_in[7];
    float* out = (float*)d_out;

    const size_t nM  = (size_t)B_ * S_ * D_;
    const size_t nW  = (size_t)D_ * D_;
    __hip_bfloat16* xb   = (__hip_bfloat16*)d_ws;
    __hip_bfloat16* wqb  = xb  + nM;
    __hip_bfloat16* wkb  = wqb + nW;
    __hip_bfloat16* wvb  = wkb + nW;
    __hip_bfloat16* wob  = wvb + nW;
    __hip_bfloat16* q_ws = wob + nW;
    __hip_bfloat16* k_ws = q_ws + nM;
    __hip_bfloat16* v_ws = k_ws + nM;
    __hip_bfloat16* a_ws = v_ws + nM;
    float2*         sct  = (float2*)(a_ws + nM);   // 65536 float2 = 512 KB

    to_bf16_kernel<<<dim3(1024, 9), 256, 0, stream>>>(
        x, w_q, w_k, w_v, w_o, sin_tab, cos_tab,
        xb, wqb, wkb, wvb, wob, sct);
    mfma_gemm_kernel<0><<<dim3(256, 1, 3), 256, 0, stream>>>(
        xb, wqb, wkb, wvb, q_ws, k_ws, v_ws, nullptr, sct, tpos);
    flash_mfma_kernel<<<dim3(8, B_ * H_), 512, 0, stream>>>(
        q_ws, k_ws, v_ws, a_ws);
    mfma_gemm_kernel<1><<<dim3(256, 1, 1), 256, 0, stream>>>(
        a_ws, wob, nullptr, nullptr, nullptr, nullptr, nullptr, out,
        sct, tpos);
}

// Round 6
// 132.415 us; speedup vs baseline: 63.4121x; 1.0572x over previous
//
#include <hip/hip_runtime.h>
#include <hip/hip_bf16.h>
#include <cstdint>

#define B_ 2
#define S_ 2048
#define D_ 1024
#define H_ 16
#define DK_ 64
#define HALF_ 32   // DK/2

typedef short bf16x8 __attribute__((ext_vector_type(8)));
typedef float f32x4  __attribute__((ext_vector_type(4)));
typedef unsigned int u32;

static __device__ __forceinline__ unsigned short bfbits(float f) {
    __hip_bfloat16 h = __float2bfloat16(f);
    unsigned short u; __builtin_memcpy(&u, &h, 2); return u;
}
static __device__ __forceinline__ unsigned pack2bf(float a, float b) {
    return (unsigned)bfbits(a) | ((unsigned)bfbits(b) << 16);
}

// async 16B global->LDS (wave-uniform LDS base + lane*16; global addr per-lane)
static __device__ __forceinline__ void gload_lds16(const void* g, void* l) {
    __builtin_amdgcn_global_load_lds(
        (const __attribute__((address_space(1))) u32*)(uintptr_t)g,
        (__attribute__((address_space(3))) u32*)(uintptr_t)l,
        16, 0, 0);
}

// ---------------------------------------------------------------------------
// Kernel 0: fp32 -> bf16 conversion (x + 4 weights) and packed (cos,sin) table.
// ---------------------------------------------------------------------------
__global__ __launch_bounds__(256) void to_bf16_kernel(
    const float* __restrict__ x,
    const float* __restrict__ wq, const float* __restrict__ wk,
    const float* __restrict__ wv, const float* __restrict__ wo,
    const float* __restrict__ sin_tab, const float* __restrict__ cos_tab,
    __hip_bfloat16* __restrict__ xb,
    __hip_bfloat16* __restrict__ wqb, __hip_bfloat16* __restrict__ wkb,
    __hip_bfloat16* __restrict__ wvb, __hip_bfloat16* __restrict__ wob,
    float2* __restrict__ sctab)
{
    const int seg = blockIdx.y;   // 0..3 x quarters; 4..7 weights; 8 sincos
    if (seg == 8) {
        if (blockIdx.x >= 64) return;     // 65536 entries / 4 per thread
        size_t i = ((size_t)blockIdx.x * 256 + threadIdx.x) * 4;
        float4 c = *reinterpret_cast<const float4*>(cos_tab + i);
        float4 s = *reinterpret_cast<const float4*>(sin_tab + i);
        float4* dst = reinterpret_cast<float4*>(sctab + i);
        dst[0] = make_float4(c.x, s.x, c.y, s.y);
        dst[1] = make_float4(c.z, s.z, c.w, s.w);
        return;
    }
    const float* src;
    __hip_bfloat16* dst;
    size_t off = 0;
    if (seg < 4)       { src = x;  dst = xb;  off = (size_t)seg << 20; }
    else if (seg == 4) { src = wq; dst = wqb; }
    else if (seg == 5) { src = wk; dst = wkb; }
    else if (seg == 6) { src = wv; dst = wvb; }
    else               { src = wo; dst = wob; }
    size_t i = off + ((size_t)blockIdx.x * 256 + threadIdx.x) * 4;
    float4 v = *reinterpret_cast<const float4*>(src + i);
    ushort4 u = make_ushort4(bfbits(v.x), bfbits(v.y), bfbits(v.z), bfbits(v.w));
    *reinterpret_cast<ushort4*>(dst + i) = u;
}

// ---------------------------------------------------------------------------
// MFMA GEMM v2 (unchanged from round 5 except Q scale constant):
// C = A @ W^T, bf16 in, 16x16x32, 128x128 tile, BK=32, dbuf, XCD swizzle.
// MODE 0: QKV + RoPE epilogue; Q pre-scaled by 0.125*log2(e) so the flash
//         softmax runs in exp2 domain. MODE 1: out-proj, fp32 out.
// ---------------------------------------------------------------------------
template<int MODE>
__global__ __launch_bounds__(256) void mfma_gemm_kernel(
    const __hip_bfloat16* __restrict__ A,
    const __hip_bfloat16* __restrict__ Wq, const __hip_bfloat16* __restrict__ Wk,
    const __hip_bfloat16* __restrict__ Wv,
    __hip_bfloat16* __restrict__ out_q, __hip_bfloat16* __restrict__ out_k,
    __hip_bfloat16* __restrict__ out_v,
    float* __restrict__ out_f32,
    const float2* __restrict__ sctab,
    const int* __restrict__ tpos)
{
    constexpr int K = 1024;
    const int which = (MODE == 0) ? blockIdx.z : 3;
    const __hip_bfloat16* __restrict__ W =
        (MODE == 1) ? Wq : (which == 0 ? Wq : which == 1 ? Wk : Wv);

    __shared__ __align__(16) unsigned char As[2][128 * 4 * 16];  // 2 x 8 KB
    __shared__ __align__(16) unsigned char Bs[2][128 * 4 * 16];  // 2 x 8 KB

    const int tid = threadIdx.x;
    const int wid = tid >> 6;
    const int l   = tid & 63;
    const int g   = l >> 4;
    const int i16 = l & 15;
    const int wr  = wid >> 1, wc = wid & 1;

    // XCD-chunked bijective swizzle: 256 blocks = 8 xcd * (4 rows x 8 cols)
    const int wg   = blockIdx.x;
    const int tile = (wg & 7) * 32 + (wg >> 3);
    const int row0 = (tile >> 3) * 128;
    const int col0 = (tile & 7) * 128;

    const __hip_bfloat16* Abase = A + (size_t)row0 * K;
    const __hip_bfloat16* Wbase = W + (size_t)col0 * K;

    f32x4 acc[4][4];
    const f32x4 zero = {0.f, 0.f, 0.f, 0.f};
    #pragma unroll
    for (int mi = 0; mi < 4; ++mi)
        #pragma unroll
        for (int ni = 0; ni < 4; ++ni) acc[mi][ni] = zero;

    int a_off[4], b_off[4];
    #pragma unroll
    for (int f = 0; f < 4; ++f) {
        int ra = wr * 64 + f * 16 + i16;
        a_off[f] = (ra * 4 + (g ^ ((ra >> 1) & 3))) * 16;
        int rb = wc * 64 + f * 16 + i16;
        b_off[f] = (rb * 4 + (g ^ ((rb >> 1) & 3))) * 16;
    }

    int st_goff[2], st_loff[2];
    #pragma unroll
    for (int it = 0; it < 2; ++it) {
        int c = it * 256 + wid * 64 + l;
        int row = c >> 2;
        int kc = (c & 3) ^ ((row >> 1) & 3);
        st_goff[it] = row * K + kc * 8;
        st_loff[it] = (it * 256 + wid * 64) * 16;
    }

    #pragma unroll
    for (int it = 0; it < 2; ++it) {
        gload_lds16(Abase + st_goff[it], &As[0][0] + st_loff[it]);
        gload_lds16(Wbase + st_goff[it], &Bs[0][0] + st_loff[it]);
    }
    __syncthreads();

    for (int t = 0; t < K / 32; ++t) {
        const int cur = t & 1;
        if (t + 1 < K / 32) {
            const int k1 = (t + 1) * 32;
            #pragma unroll
            for (int it = 0; it < 2; ++it) {
                gload_lds16(Abase + k1 + st_goff[it], &As[cur ^ 1][0] + st_loff[it]);
                gload_lds16(Wbase + k1 + st_goff[it], &Bs[cur ^ 1][0] + st_loff[it]);
            }
        }
        bf16x8 af[4], bfr[4];
        #pragma unroll
        for (int f = 0; f < 4; ++f) {
            af[f]  = *reinterpret_cast<const bf16x8*>(&As[cur][0] + a_off[f]);
            bfr[f] = *reinterpret_cast<const bf16x8*>(&Bs[cur][0] + b_off[f]);
        }
        #pragma unroll
        for (int mi = 0; mi < 4; ++mi)
            #pragma unroll
            for (int ni = 0; ni < 4; ++ni)
                acc[mi][ni] = __builtin_amdgcn_mfma_f32_16x16x32_bf16(
                    af[mi], bfr[ni], acc[mi][ni], 0, 0, 0);
        __syncthreads();
    }

    if (MODE == 0) {
        __hip_bfloat16* __restrict__ outp =
            which == 0 ? out_q : which == 1 ? out_k : out_v;
        const int head = (col0 >> 6) + wc;
        #pragma unroll
        for (int mi = 0; mi < 4; ++mi) {
            #pragma unroll
            for (int r = 0; r < 4; ++r) {
                const int gi = row0 + wr * 64 + mi * 16 + g * 4 + r;
                const int b_ = gi >> 11;
                const int s_ = gi & (S_ - 1);
                const int pos = tpos[gi];
                const float2* sc = sctab + pos * HALF_;
                __hip_bfloat16* orow =
                    outp + (((size_t)b_ * H_ + head) * S_ + s_) * DK_;
                #pragma unroll
                for (int ni = 0; ni < 4; ++ni) {
                    float val = acc[mi][ni][r];
                    float other = __shfl_xor(val, 1, 64);
                    const int dk = ni * 16 + i16;
                    float res;
                    if (which < 2) {
                        float2 cs = sc[ni * 8 + (i16 >> 1)];
                        res = (i16 & 1) ? fmaf(cs.y, other, cs.x * val)
                                        : (cs.x * val - cs.y * other);
                    } else {
                        res = val;
                    }
                    // 0.125 * log2(e): softmax runs in exp2 domain
                    if (which == 0) res *= 0.180336880f;
                    orow[dk] = __float2bfloat16(res);
                }
            }
        }
    } else {
        #pragma unroll
        for (int mi = 0; mi < 4; ++mi) {
            #pragma unroll
            for (int r = 0; r < 4; ++r) {
                const int gi = row0 + wr * 64 + mi * 16 + g * 4 + r;
                float* orow = out_f32 + (size_t)gi * D_ + col0 + wc * 64;
                #pragma unroll
                for (int ni = 0; ni < 4; ++ni)
                    orow[ni * 16 + i16] = acc[mi][ni][r];
            }
        }
    }
}

// ---------------------------------------------------------------------------
// Kernel 2 (v3): causal flash attention, bf16 MFMA 16x16x32.
//  - one 128-row q-superblock per block, 8 waves; grid 512 = 2 blocks/CU
//    (cross-block overlap hides the per-tile serial chain)
//  - swizzle: xcd = wgid&7 owns bh in {4*xcd..4*xcd+3} (K/V L2-resident),
//    qsb = 15 - (wgid>>5) -> largest blocks dispatched first
//  - log2-domain softmax (Q pre-scaled by 0.125*log2e): p = exp2(s - m)
//  - T13 defer-max (THR=11.5 log2-units): skip rescale when max stable
//  - K via global_load_lds, V^T reg-scatter, both double-buffered, one
//    barrier per tile; all LDS chunk-swizzled
// ---------------------------------------------------------------------------
__global__ __launch_bounds__(512) void flash_mfma_kernel(
    const __hip_bfloat16* __restrict__ q,   // (b,h,s,dk), pre-scaled
    const __hip_bfloat16* __restrict__ k,
    const __hip_bfloat16* __restrict__ v,
    __hip_bfloat16* __restrict__ attn)      // (b,s,D) bf16
{
    __shared__ __align__(16) unsigned char Ks[2][64 * 128];
    __shared__ __align__(16) unsigned char Vt[2][64 * 128];
    __shared__ __align__(16) unsigned char Ps[8][16 * 128];

    const int tid = threadIdx.x;
    const int w   = tid >> 6;
    const int l   = tid & 63;
    const int g   = l >> 4;
    const int i16 = l & 15;

    // block swizzle: bh locality per XCD + largest-first
    const int wgid = blockIdx.x;              // 0..511
    const int bh   = (wgid & 7) * 4 + ((wgid >> 3) & 3);
    const int qsb  = 15 - (wgid >> 5);

    const size_t base = (size_t)bh * S_ * DK_;
    const __hip_bfloat16* kb_ = k + base;
    const __hip_bfloat16* vb_ = v + base;

    const int ci     = w * 64 + l;
    const int krow   = ci >> 3;
    const int kchunk = (ci & 7) ^ (krow & 7);
    const int ksrc   = krow * DK_ + kchunk * 8;
    unsigned char* const pw = &Ps[w][0];

    const int qrow  = qsb * 128 + w * 16 + i16;
    const int qbase = qsb * 128 + w * 16;
    const int nt    = 2 * qsb + 2;

    bf16x8 qf0, qf1;
    {
        const __hip_bfloat16* qp = q + base + (size_t)qrow * DK_ + g * 8;
        qf0 = *reinterpret_cast<const bf16x8*>(qp);
        qf1 = *reinterpret_cast<const bf16x8*>(qp + 32);
    }

    f32x4 o[4] = {};
    float m_run = -1e30f, l_run = 0.0f;

    gload_lds16(kb_ + ksrc, &Ks[0][0] + w * 1024);
    {
        float4 vv = *reinterpret_cast<const float4*>(vb_ + l * DK_ + w * 8);
        const unsigned short* u = reinterpret_cast<const unsigned short*>(&vv);
        #pragma unroll
        for (int s = 0; s < 8; ++s) {
            int d = w * 8 + s;
            *reinterpret_cast<unsigned short*>(&Vt[0][0] + d * 128 +
                (((l >> 3) ^ (d & 7)) << 4) + (l & 7) * 2) = u[s];
        }
    }
    __syncthreads();

    for (int t = 0; t < nt; ++t) {
        const int cur = t & 1;
        const bool pre = (t + 1 < nt);
        float4 vv;
        if (pre) {
            gload_lds16(kb_ + (size_t)(t + 1) * 64 * DK_ + ksrc,
                        &Ks[cur ^ 1][0] + w * 1024);
            vv = *reinterpret_cast<const float4*>(
                vb_ + (size_t)(t + 1) * 64 * DK_ + l * DK_ + w * 8);
        }

        if (t * 64 <= qbase + 15) {
            // ---- S^T = K . Q^T ----
            f32x4 s_acc[4] = {};
            __builtin_amdgcn_s_setprio(1);
            #pragma unroll
            for (int jf = 0; jf < 4; ++jf) {
                int row = jf * 16 + i16;
                bf16x8 ak0 = *reinterpret_cast<const bf16x8*>(
                    &Ks[cur][0] + row * 128 + ((g ^ (row & 7)) << 4));
                s_acc[jf] = __builtin_amdgcn_mfma_f32_16x16x32_bf16(
                    ak0, qf0, s_acc[jf], 0, 0, 0);
                bf16x8 ak1 = *reinterpret_cast<const bf16x8*>(
                    &Ks[cur][0] + row * 128 + (((4 + g) ^ (row & 7)) << 4));
                s_acc[jf] = __builtin_amdgcn_mfma_f32_16x16x32_bf16(
                    ak1, qf1, s_acc[jf], 0, 0, 0);
            }
            __builtin_amdgcn_s_setprio(0);

            // ---- causal mask (near-diagonal tiles only) ----
            if (t * 64 + 63 > qbase) {
                #pragma unroll
                for (int jf = 0; jf < 4; ++jf)
                    #pragma unroll
                    for (int r = 0; r < 4; ++r)
                        if (t * 64 + jf * 16 + g * 4 + r > qrow)
                            s_acc[jf][r] = -1e30f;
            }

            // ---- row max (tree) ----
            float mx01 = fmaxf(fmaxf(s_acc[0][0], s_acc[0][1]),
                               fmaxf(s_acc[0][2], s_acc[0][3]));
            float mx02 = fmaxf(fmaxf(s_acc[1][0], s_acc[1][1]),
                               fmaxf(s_acc[1][2], s_acc[1][3]));
            float mx03 = fmaxf(fmaxf(s_acc[2][0], s_acc[2][1]),
                               fmaxf(s_acc[2][2], s_acc[2][3]));
            float mx04 = fmaxf(fmaxf(s_acc[3][0], s_acc[3][1]),
                               fmaxf(s_acc[3][2], s_acc[3][3]));
            float vmax = fmaxf(fmaxf(mx01, mx02), fmaxf(mx03, mx04));
            vmax = fmaxf(vmax, __shfl_xor(vmax, 16, 64));
            vmax = fmaxf(vmax, __shfl_xor(vmax, 32, 64));

            // ---- defer-max: rescale only if max grew past THR ----
            if (!__all(vmax <= m_run + 11.5f)) {
                float m_new = fmaxf(m_run, vmax);
                float factor = __builtin_amdgcn_exp2f(m_run - m_new);
                m_run = m_new;
                l_run *= factor;
                #pragma unroll
                for (int df = 0; df < 4; ++df)
                    #pragma unroll
                    for (int r = 0; r < 4; ++r)
                        o[df][r] *= factor;
            }

            // ---- P = exp2(S - m), row-sum ----
            float p[4][4];
            float psum = 0.0f;
            #pragma unroll
            for (int jf = 0; jf < 4; ++jf)
                #pragma unroll
                for (int r = 0; r < 4; ++r) {
                    p[jf][r] = __builtin_amdgcn_exp2f(s_acc[jf][r] - m_run);
                    psum += p[jf][r];
                }
            psum += __shfl_xor(psum, 16, 64);
            psum += __shfl_xor(psum, 32, 64);
            l_run += psum;

            // ---- pack P -> bf16, wave-local LDS (swizzled) ----
            #pragma unroll
            for (int jf = 0; jf < 4; ++jf)
                #pragma unroll
                for (int r0 = 0; r0 < 4; r0 += 2) {
                    unsigned pk = pack2bf(p[jf][r0], p[jf][r0 + 1]);
                    int jj = jf * 16 + g * 4 + r0;
                    *reinterpret_cast<unsigned*>(pw + i16 * 128 +
                        ((jj * 2) ^ ((i16 & 7) << 4))) = pk;
                }

            // ---- O^T += V^T . P^T ----
            __builtin_amdgcn_s_setprio(1);
            #pragma unroll
            for (int jc = 0; jc < 2; ++jc) {
                bf16x8 bp = *reinterpret_cast<const bf16x8*>(pw + i16 * 128 +
                    (((jc * 4 + g) ^ (i16 & 7)) << 4));
                #pragma unroll
                for (int df = 0; df < 4; ++df) {
                    int row = df * 16 + i16;
                    bf16x8 av = *reinterpret_cast<const bf16x8*>(
                        &Vt[cur][0] + row * 128 +
                        (((jc * 4 + g) ^ (row & 7)) << 4));
                    o[df] = __builtin_amdgcn_mfma_f32_16x16x32_bf16(
                        av, bp, o[df], 0, 0, 0);
                }
            }
            __builtin_amdgcn_s_setprio(0);
        }

        if (pre) {
            const unsigned short* u = reinterpret_cast<const unsigned short*>(&vv);
            unsigned char* vtb = &Vt[cur ^ 1][0];
            #pragma unroll
            for (int s = 0; s < 8; ++s) {
                int d = w * 8 + s;
                *reinterpret_cast<unsigned short*>(vtb + d * 128 +
                    (((l >> 3) ^ (d & 7)) << 4) + (l & 7) * 2) = u[s];
            }
        }
        __syncthreads();
    }

    // ---- normalize + store ----
    const float inv_l = 1.0f / l_run;
    const int b_ = bh >> 4, h_ = bh & 15;
    __hip_bfloat16* orow = attn + ((size_t)b_ * S_ + qrow) * D_ + h_ * 64;
    #pragma unroll
    for (int df = 0; df < 4; ++df) {
        ushort4 uo = make_ushort4(
            bfbits(o[df][0] * inv_l), bfbits(o[df][1] * inv_l),
            bfbits(o[df][2] * inv_l), bfbits(o[df][3] * inv_l));
        *reinterpret_cast<ushort4*>(orow + df * 16 + g * 4) = uo;
    }
}

// ---------------------------------------------------------------------------
extern "C" void kernel_launch(void* const* d_in, const int* in_sizes, int n_in,
                              void* d_out, int out_size, void* d_ws, size_t ws_size,
                              hipStream_t stream) {
    const float* x       = (const float*)d_in[0];
    const float* w_q     = (const float*)d_in[1];
    const float* w_k     = (const float*)d_in[2];
    const float* w_v     = (const float*)d_in[3];
    const float* w_o     = (const float*)d_in[4];
    const float* sin_tab = (const float*)d_in[5];
    const float* cos_tab = (const float*)d_in[6];
    const int*   tpos    = (const int*)d_in[7];
    float* out = (float*)d_out;

    const size_t nM  = (size_t)B_ * S_ * D_;
    const size_t nW  = (size_t)D_ * D_;
    __hip_bfloat16* xb   = (__hip_bfloat16*)d_ws;
    __hip_bfloat16* wqb  = xb  + nM;
    __hip_bfloat16* wkb  = wqb + nW;
    __hip_bfloat16* wvb  = wkb + nW;
    __hip_bfloat16* wob  = wvb + nW;
    __hip_bfloat16* q_ws = wob + nW;
    __hip_bfloat16* k_ws = q_ws + nM;
    __hip_bfloat16* v_ws = k_ws + nM;
    __hip_bfloat16* a_ws = v_ws + nM;
    float2*         sct  = (float2*)(a_ws + nM);   // 65536 float2 = 512 KB

    to_bf16_kernel<<<dim3(1024, 9), 256, 0, stream>>>(
        x, w_q, w_k, w_v, w_o, sin_tab, cos_tab,
        xb, wqb, wkb, wvb, wob, sct);
    mfma_gemm_kernel<0><<<dim3(256, 1, 3), 256, 0, stream>>>(
        xb, wqb, wkb, wvb, q_ws, k_ws, v_ws, nullptr, sct, tpos);
    flash_mfma_kernel<<<512, 512, 0, stream>>>(
        q_ws, k_ws, v_ws, a_ws);
    mfma_gemm_kernel<1><<<dim3(256, 1, 1), 256, 0, stream>>>(
        a_ws, wob, nullptr, nullptr, nullptr, nullptr, nullptr, out,
        sct, tpos);
}